// Round 1
// 830.451 us; speedup vs baseline: 2.1676x; 2.1676x over previous
//
#include <hip/hip_runtime.h>
#include <hip/hip_bf16.h>
#include <math.h>

typedef unsigned short u16;

#define BB 4
#define CC 512
#define HH 128
#define WW 128
#define PP (HH*WW)   // 16384 spatial positions per batch

#define NEG_BIG (-3.0e38f)

typedef float f32x4 __attribute__((ext_vector_type(4)));
typedef __bf16 bf16x8 __attribute__((ext_vector_type(8)));

__device__ __forceinline__ float bf2f(u16 u) {
    union { unsigned int i; float f; } v; v.i = ((unsigned int)u) << 16; return v.f;
}
__device__ __forceinline__ u16 f2bf(float f) {
    __hip_bfloat16 h = __float2bfloat16(f);
    u16 u; __builtin_memcpy(&u, &h, 2); return u;
}

template<bool F32>
__device__ __forceinline__ float ldg(const void* p, size_t i) {
    if (F32) return ((const float*)p)[i];
    return bf2f(((const u16*)p)[i]);
}

// async global->LDS, 16B per lane; LDS dest = wave-uniform base + lane*16
__device__ __forceinline__ void gl2lds16(const void* g, void* l) {
    __builtin_amdgcn_global_load_lds(
        (const __attribute__((address_space(1))) unsigned int*)g,
        (__attribute__((address_space(3))) unsigned int*)l,
        16, 0, 0);
}

// ---------------------------------------------------------------------------
// K0: input dtype detection (flag=1 -> fp32).
// ---------------------------------------------------------------------------
__global__ __launch_bounds__(256) void detect_kernel(const void* x, int* flag)
{
    const int t = threadIdx.x;
    const unsigned int* w = (const unsigned int*)x;
    int cnt = 0;
#pragma unroll
    for (int s = 0; s < 16; s++) {
        unsigned int v = w[t * 16 + s];
        int e = (v >> 7) & 0xFF;
        cnt += (e >= 100 && e < 132) ? 1 : 0;
    }
    __shared__ int sh[256];
    sh[t] = cnt;
    __syncthreads();
    for (int o = 128; o; o >>= 1) {
        if (t < o) sh[t] += sh[t + o];
        __syncthreads();
    }
    if (t == 0) *flag = (sh[0] < 2048) ? 1 : 0;
}

// ---------------------------------------------------------------------------
// K0b: weight/bias conversion (once).  Concatenated rows: [Wq;Wk;Wv] -> [640][512]
// hi/lo bf16 split (W = W_hi + W_lo to ~2^-17 rel).  bcat fp32 [640].
// ---------------------------------------------------------------------------
template<bool F32>
__device__ __forceinline__ void wconv_body(
    const void* Wq, const void* bq, const void* Wk, const void* bk,
    const void* Wv, const void* bv,
    u16* __restrict__ Wh, u16* __restrict__ Wl, float* __restrict__ bcat)
{
    const int o = blockIdx.x;
    const int t = threadIdx.x;
#pragma unroll
    for (int s = 0; s < 2; s++) {
        int c = t + s * 256;
        float v;
        if (o < 64)       v = ldg<F32>(Wq, (size_t)o * CC + c);
        else if (o < 128) v = ldg<F32>(Wk, (size_t)(o - 64) * CC + c);
        else              v = ldg<F32>(Wv, (size_t)(o - 128) * CC + c);
        u16 h = f2bf(v);
        Wh[(size_t)o * CC + c] = h;
        Wl[(size_t)o * CC + c] = f2bf(v - bf2f(h));
    }
    if (t == 0) {
        bcat[o] = (o < 64) ? ldg<F32>(bq, o)
                : (o < 128) ? ldg<F32>(bk, o - 64)
                : ldg<F32>(bv, o - 128);
    }
}

__global__ __launch_bounds__(256) void wconv_kernel(
    const void* Wq, const void* bq, const void* Wk, const void* bk,
    const void* Wv, const void* bv, const int* __restrict__ dflag,
    u16* Wh, u16* Wl, float* bcat)
{
    if (*dflag) wconv_body<true >(Wq, bq, Wk, bk, Wv, bv, Wh, Wl, bcat);
    else        wconv_body<false>(Wq, bq, Wk, bk, Wv, bv, Wh, Wl, bcat);
}

// ---------------------------------------------------------------------------
// K0c: per-batch transpose+split: x [512][16384] -> xT_hi/xT_lo [16384][512] bf16.
// 64x64 LDS tile.  bf16 input: hi = identity, lo = 0 (uniform code path).
// ---------------------------------------------------------------------------
template<bool F32>
__device__ __forceinline__ void trans_body(
    const void* __restrict__ x, u16* __restrict__ xh, u16* __restrict__ xl,
    float (*T)[65])
{
    const int t = threadIdx.x;
    const int p0 = blockIdx.x * 64;
    const int c0 = blockIdx.y * 64;
    {
        const int pp = t & 63;
        const int cb = t >> 6;   // 0..3
#pragma unroll
        for (int s = 0; s < 16; s++) {
            int cc = cb * 16 + s;
            T[cc][pp] = ldg<F32>(x, (size_t)(c0 + cc) * PP + p0 + pp);
        }
    }
    __syncthreads();
    {
        const int pr = t >> 2;          // 0..63
        const int cb = (t & 3) * 16;    // 0,16,32,48
        u16 hi[16], lo[16];
#pragma unroll
        for (int j = 0; j < 16; j++) {
            float v = T[cb + j][pr];
            u16 h = f2bf(v);
            hi[j] = h;
            lo[j] = f2bf(v - bf2f(h));
        }
        size_t base = (size_t)(p0 + pr) * 512 + c0 + cb;
#pragma unroll
        for (int s = 0; s < 4; s++) {
            *(ushort4*)(xh + base + s * 4) = *(ushort4*)(hi + s * 4);
            *(ushort4*)(xl + base + s * 4) = *(ushort4*)(lo + s * 4);
        }
    }
}

__global__ __launch_bounds__(256) void trans_kernel(
    const void* x_f32, const void* x_b16, const int* __restrict__ dflag,
    u16* xh, u16* xl)
{
    __shared__ float T[64][65];
    if (*dflag) trans_body<true >(x_f32, xh, xl, T);
    else        trans_body<false>(x_b16, xh, xl, T);
}

// ---------------------------------------------------------------------------
// K1: MFMA split-GEMM projection.  C[p][o] = sum_k' A'[p][k'] B'[o][k'],
// K'=1536: k'<512: x_hi.W_hi | <1024: x_hi.W_lo | <1536: x_lo.W_hi
// (== W.x to ~2^-17; dropped W_lo.x_lo term is negligible).
// 128x128 tile, 4 waves (2x2 of 64x64), mfma_f32_16x16x32_bf16 4x4 frags.
// LDS tiles [128 rows][32 k] bf16 with chunk-XOR swizzle (both-sides):
//   LDS(row, chunk) holds global chunk (chunk ^ (row&3))  -> 2-way-free ds_read_b128.
// Staged via global_load_lds width=16 (pre-swizzled global source).
// o<64 -> q_t fp32 [p][64]; o<128 -> k_t fp32; o>=128 -> v_t bf16 [p][512].
// ---------------------------------------------------------------------------
__global__ __launch_bounds__(256) void projmm_kernel(
    const u16* __restrict__ xT_hi, const u16* __restrict__ xT_lo,
    const u16* __restrict__ W_hi,  const u16* __restrict__ W_lo,
    const float* __restrict__ bcat,
    float* __restrict__ q_t, float* __restrict__ k_t, u16* __restrict__ v_t)
{
    __shared__ u16 Asl[128 * 32];
    __shared__ u16 Bsl[128 * 32];
    const int t = threadIdx.x;
    const int lane = t & 63, wid = t >> 6;
    const int wr = wid >> 1, wc = wid & 1;
    const int fr = lane & 15, fq = lane >> 4;
    const int p0 = blockIdx.x * 128;
    const int o0 = blockIdx.y * 128;

    f32x4 acc[4][4];
#pragma unroll
    for (int i = 0; i < 4; i++)
#pragma unroll
        for (int j = 0; j < 4; j++) acc[i][j] = (f32x4){0.f, 0.f, 0.f, 0.f};

    // staging: wave wid owns chunks {2wid, 2wid+1}; chunk = 16 rows x 32 k = 1KB.
    // LDS elem L = ch*512 + lane*8 -> (row = ch*16 + lane/4, kchunk_l = lane&3);
    // source global k-chunk = kchunk_l ^ (row&3)  (the swizzle).
    const int srow0  = wid * 32 + (lane >> 2);
    const int kchunk = (lane & 3) ^ ((lane >> 2) & 3);
    const size_t gA0 = (size_t)(p0 + srow0) * 512 + kchunk * 8;
    const size_t gA1 = gA0 + (size_t)16 * 512;
    const size_t gB0 = (size_t)(o0 + srow0) * 512 + kchunk * 8;
    const size_t gB1 = gB0 + (size_t)16 * 512;
    u16* ldsA = Asl + wid * 1024;
    u16* ldsB = Bsl + wid * 1024;

    // fragment read offsets (inverse of the same involution)
    int aoff[4], boff[4];
#pragma unroll
    for (int mi = 0; mi < 4; mi++) {
        int row = wr * 64 + mi * 16 + fr;
        aoff[mi] = row * 32 + ((fq ^ (row & 3)) * 8);
    }
#pragma unroll
    for (int ni = 0; ni < 4; ni++) {
        int row = wc * 64 + ni * 16 + fr;
        boff[ni] = row * 32 + ((fq ^ (row & 3)) * 8);
    }

    for (int k0 = 0; k0 < 1536; k0 += 32) {
        const int rg = k0 >> 9;          // 0,1,2 (uniform)
        const int kc = k0 & 511;
        const u16* xs   = (rg == 2) ? xT_lo : xT_hi;
        const u16* wsrc = (rg == 1) ? W_lo  : W_hi;
        gl2lds16(xs + gA0 + kc, ldsA);
        gl2lds16(xs + gA1 + kc, ldsA + 512);
        gl2lds16(wsrc + gB0 + kc, ldsB);
        gl2lds16(wsrc + gB1 + kc, ldsB + 512);
        __syncthreads();                  // drains vmcnt before barrier

        bf16x8 av[4], bv8[4];
#pragma unroll
        for (int mi = 0; mi < 4; mi++) av[mi] = *(const bf16x8*)(Asl + aoff[mi]);
#pragma unroll
        for (int ni = 0; ni < 4; ni++) bv8[ni] = *(const bf16x8*)(Bsl + boff[ni]);
#pragma unroll
        for (int mi = 0; mi < 4; mi++)
#pragma unroll
            for (int ni = 0; ni < 4; ni++)
                acc[mi][ni] = __builtin_amdgcn_mfma_f32_16x16x32_bf16(
                    av[mi], bv8[ni], acc[mi][ni], 0, 0, 0);
        __syncthreads();                  // protect LDS before next stage
    }

    // epilogue: C row p = p0+wr*64+mi*16+fq*4+r, col o = o0+wc*64+ni*16+fr
#pragma unroll
    for (int ni = 0; ni < 4; ni++) {
        const int o = o0 + wc * 64 + ni * 16 + fr;
        const float bb = bcat[o];
        if (o < 64) {
#pragma unroll
            for (int mi = 0; mi < 4; mi++) {
                const int pb = p0 + wr * 64 + mi * 16 + fq * 4;
#pragma unroll
                for (int r = 0; r < 4; r++)
                    q_t[(size_t)(pb + r) * 64 + o] = acc[mi][ni][r] + bb;
            }
        } else if (o < 128) {
#pragma unroll
            for (int mi = 0; mi < 4; mi++) {
                const int pb = p0 + wr * 64 + mi * 16 + fq * 4;
#pragma unroll
                for (int r = 0; r < 4; r++)
                    k_t[(size_t)(pb + r) * 64 + (o - 64)] = acc[mi][ni][r] + bb;
            }
        } else {
#pragma unroll
            for (int mi = 0; mi < 4; mi++) {
                const int pb = p0 + wr * 64 + mi * 16 + fq * 4;
#pragma unroll
                for (int r = 0; r < 4; r++)
                    v_t[(size_t)(pb + r) * 512 + (o - 128)] = f2bf(acc[mi][ni][r] + bb);
            }
        }
    }
}

// ---------------------------------------------------------------------------
// K2: energy_H.  Block per w: E[h][i] = sum_c q[h,w,c]*k[i,w,c]; diag -> NEG_BIG.
// ---------------------------------------------------------------------------
__global__ __launch_bounds__(256) void energyH_kernel(
    const float* __restrict__ q_t, const float* __restrict__ k_t,
    float* __restrict__ attn_f)
{
    const int w = blockIdx.x;
    const int t = threadIdx.x, tx = t & 15, ty = t >> 4;
    __shared__ float Qs[32][128];
    __shared__ float Ks[32][128];
    float acc[8][8];
#pragma unroll
    for (int i = 0; i < 8; i++)
#pragma unroll
        for (int j = 0; j < 8; j++) acc[i][j] = 0.f;

    for (int cb = 0; cb < 2; cb++) {
        const int hh = t >> 1;
        const int cl0 = (t & 1) * 16;
        const int cg0 = cb * 32 + cl0;
        const float4* q4 = (const float4*)(q_t + (size_t)(hh * WW + w) * 64 + cg0);
        const float4* k4 = (const float4*)(k_t + (size_t)(hh * WW + w) * 64 + cg0);
#pragma unroll
        for (int s = 0; s < 4; s++) {
            float4 qv = q4[s], kv = k4[s];
            int c = cl0 + s * 4;
            Qs[c][hh] = qv.x; Qs[c + 1][hh] = qv.y; Qs[c + 2][hh] = qv.z; Qs[c + 3][hh] = qv.w;
            Ks[c][hh] = kv.x; Ks[c + 1][hh] = kv.y; Ks[c + 2][hh] = kv.z; Ks[c + 3][hh] = kv.w;
        }
        __syncthreads();
#pragma unroll 4
        for (int c = 0; c < 32; c++) {
            float a[8], bb[8];
#pragma unroll
            for (int i = 0; i < 8; i++) a[i] = Qs[c][ty * 8 + i];
#pragma unroll
            for (int j = 0; j < 8; j++) bb[j] = Ks[c][tx * 8 + j];
#pragma unroll
            for (int i = 0; i < 8; i++)
#pragma unroll
                for (int j = 0; j < 8; j++)
                    acc[i][j] = fmaf(a[i], bb[j], acc[i][j]);
        }
        __syncthreads();
    }
#pragma unroll
    for (int i = 0; i < 8; i++) {
        int h = ty * 8 + i;
        float* row = attn_f + (size_t)(h * WW + w) * 256;
        float v[8];
#pragma unroll
        for (int j = 0; j < 8; j++) {
            int ic = tx * 8 + j;
            v[j] = (ic == h) ? NEG_BIG : acc[i][j];
        }
        ((float4*)(row + tx * 8))[0] = make_float4(v[0], v[1], v[2], v[3]);
        ((float4*)(row + tx * 8))[1] = make_float4(v[4], v[5], v[6], v[7]);
    }
}

// ---------------------------------------------------------------------------
// K3: energy_W.  Block per h: E[w][j] = sum_c q[h,w,c]*k[h,j,c].
// ---------------------------------------------------------------------------
__global__ __launch_bounds__(256) void energyW_kernel(
    const float* __restrict__ q_t, const float* __restrict__ k_t,
    float* __restrict__ attn_f)
{
    const int h = blockIdx.x;
    const int t = threadIdx.x, tx = t & 15, ty = t >> 4;
    __shared__ float Qs[32][128];
    __shared__ float Ks[32][128];
    float acc[8][8];
#pragma unroll
    for (int i = 0; i < 8; i++)
#pragma unroll
        for (int j = 0; j < 8; j++) acc[i][j] = 0.f;

    for (int cb = 0; cb < 2; cb++) {
        const int ww = t >> 1;
        const int cl0 = (t & 1) * 16;
        const int cg0 = cb * 32 + cl0;
        const float4* q4 = (const float4*)(q_t + (size_t)(h * WW + ww) * 64 + cg0);
        const float4* k4 = (const float4*)(k_t + (size_t)(h * WW + ww) * 64 + cg0);
#pragma unroll
        for (int s = 0; s < 4; s++) {
            float4 qv = q4[s], kv = k4[s];
            int c = cl0 + s * 4;
            Qs[c][ww] = qv.x; Qs[c + 1][ww] = qv.y; Qs[c + 2][ww] = qv.z; Qs[c + 3][ww] = qv.w;
            Ks[c][ww] = kv.x; Ks[c + 1][ww] = kv.y; Ks[c + 2][ww] = kv.z; Ks[c + 3][ww] = kv.w;
        }
        __syncthreads();
#pragma unroll 4
        for (int c = 0; c < 32; c++) {
            float a[8], bb[8];
#pragma unroll
            for (int i = 0; i < 8; i++) a[i] = Qs[c][ty * 8 + i];
#pragma unroll
            for (int j = 0; j < 8; j++) bb[j] = Ks[c][tx * 8 + j];
#pragma unroll
            for (int i = 0; i < 8; i++)
#pragma unroll
                for (int j = 0; j < 8; j++)
                    acc[i][j] = fmaf(a[i], bb[j], acc[i][j]);
        }
        __syncthreads();
    }
#pragma unroll
    for (int i = 0; i < 8; i++) {
        int w = ty * 8 + i;
        float* row = attn_f + (size_t)(h * WW + w) * 256 + 128;
        ((float4*)(row + tx * 8))[0] = make_float4(acc[i][0], acc[i][1], acc[i][2], acc[i][3]);
        ((float4*)(row + tx * 8))[1] = make_float4(acc[i][4], acc[i][5], acc[i][6], acc[i][7]);
    }
}

// ---------------------------------------------------------------------------
// K4: softmax over 256, one wave per row, fp32 -> bf16, finite-guarded.
// ---------------------------------------------------------------------------
__global__ __launch_bounds__(256) void softmax_kernel(
    const float* __restrict__ attn_f, u16* __restrict__ attn_b)
{
    const int wave = threadIdx.x >> 6, lane = threadIdx.x & 63;
    const size_t row = (size_t)blockIdx.x * 4 + wave;
    const float* rp = attn_f + row * 256;
    float4 v = ((const float4*)rp)[lane];
    v.x = isfinite(v.x) ? v.x : NEG_BIG;
    v.y = isfinite(v.y) ? v.y : NEG_BIG;
    v.z = isfinite(v.z) ? v.z : NEG_BIG;
    v.w = isfinite(v.w) ? v.w : NEG_BIG;
    float m = fmaxf(fmaxf(v.x, v.y), fmaxf(v.z, v.w));
#pragma unroll
    for (int off = 32; off; off >>= 1) m = fmaxf(m, __shfl_xor(m, off));
    float e0 = __expf(v.x - m), e1 = __expf(v.y - m);
    float e2 = __expf(v.z - m), e3 = __expf(v.w - m);
    float s = e0 + e1 + e2 + e3;
#pragma unroll
    for (int off = 32; off; off >>= 1) s += __shfl_xor(s, off);
    float inv = 1.0f / s;
    ushort4 u = { f2bf(e0 * inv), f2bf(e1 * inv), f2bf(e2 * inv), f2bf(e3 * inv) };
    ((ushort4*)(attn_b + row * 256))[lane] = u;
}

// ---------------------------------------------------------------------------
// K5: column aggregation.
// ---------------------------------------------------------------------------
__global__ __launch_bounds__(256) void aggA_kernel(
    const u16* __restrict__ v_t, const u16* __restrict__ attn_b,
    u16* __restrict__ out_t)
{
    const int c0 = blockIdx.x * 128, w = blockIdx.y;
    const int t = threadIdx.x, tx = t & 15, ty = t >> 4;
    __shared__ float Vs[16][128];
    __shared__ float As[16][132];
    float acc[8][8];
#pragma unroll
    for (int i = 0; i < 8; i++)
#pragma unroll
        for (int j = 0; j < 8; j++) acc[i][j] = 0.f;

    for (int i0 = 0; i0 < HH; i0 += 16) {
#pragma unroll
        for (int s = 0; s < 2; s++) {
            int e = t + 256 * s;
            int cc = (e & 31) * 4, ii = e >> 5;
            ushort4 u = *(const ushort4*)(v_t + (size_t)((i0 + ii) * WW + w) * 512 + c0 + cc);
            Vs[ii][cc + 0] = bf2f(u.x); Vs[ii][cc + 1] = bf2f(u.y);
            Vs[ii][cc + 2] = bf2f(u.z); Vs[ii][cc + 3] = bf2f(u.w);
        }
#pragma unroll
        for (int s = 0; s < 8; s++) {
            int e = t + 256 * s;
            int ii = e & 15, hh = e >> 4;
            As[ii][hh] = bf2f(attn_b[(size_t)(hh * WW + w) * 256 + i0 + ii]);
        }
        __syncthreads();
#pragma unroll
        for (int ii = 0; ii < 16; ii++) {
            float vv[8], aa[8];
#pragma unroll
            for (int ci = 0; ci < 8; ci++) vv[ci] = Vs[ii][tx * 8 + ci];
#pragma unroll
            for (int hj = 0; hj < 8; hj++) aa[hj] = As[ii][ty * 8 + hj];
#pragma unroll
            for (int ci = 0; ci < 8; ci++)
#pragma unroll
                for (int hj = 0; hj < 8; hj++)
                    acc[ci][hj] = fmaf(vv[ci], aa[hj], acc[ci][hj]);
        }
        __syncthreads();
    }
#pragma unroll
    for (int hj = 0; hj < 8; hj++) {
        int h = ty * 8 + hj;
        ushort4 u0 = { f2bf(acc[0][hj]), f2bf(acc[1][hj]), f2bf(acc[2][hj]), f2bf(acc[3][hj]) };
        ushort4 u1 = { f2bf(acc[4][hj]), f2bf(acc[5][hj]), f2bf(acc[6][hj]), f2bf(acc[7][hj]) };
        ushort4* dst = (ushort4*)(out_t + (size_t)(h * WW + w) * 512 + c0 + tx * 8);
        dst[0] = u0; dst[1] = u1;
    }
}

// ---------------------------------------------------------------------------
// K6: row aggregation + fused epilogue.
// ---------------------------------------------------------------------------
template<bool F32>
__device__ __forceinline__ void aggB_body(
    const u16* __restrict__ v_t, const u16* __restrict__ attn_b,
    const u16* __restrict__ out_t, const void* __restrict__ x,
    const void* __restrict__ gamma, void* __restrict__ out,
    float (*Vs)[128], float (*As)[132])
{
    const int c0 = blockIdx.x * 128, h = blockIdx.y;
    const int t = threadIdx.x, tx = t & 15, ty = t >> 4;
    float acc[8][8];
#pragma unroll
    for (int i = 0; i < 8; i++)
#pragma unroll
        for (int j = 0; j < 8; j++) acc[i][j] = 0.f;

    for (int j0 = 0; j0 < WW; j0 += 16) {
#pragma unroll
        for (int s = 0; s < 2; s++) {
            int e = t + 256 * s;
            int cc = (e & 31) * 4, jj = e >> 5;
            ushort4 u = *(const ushort4*)(v_t + (size_t)(h * WW + j0 + jj) * 512 + c0 + cc);
            Vs[jj][cc + 0] = bf2f(u.x); Vs[jj][cc + 1] = bf2f(u.y);
            Vs[jj][cc + 2] = bf2f(u.z); Vs[jj][cc + 3] = bf2f(u.w);
        }
#pragma unroll
        for (int s = 0; s < 8; s++) {
            int e = t + 256 * s;
            int jj = e & 15, ww = e >> 4;
            As[jj][ww] = bf2f(attn_b[(size_t)(h * WW + ww) * 256 + 128 + j0 + jj]);
        }
        __syncthreads();
#pragma unroll
        for (int jj = 0; jj < 16; jj++) {
            float vv[8], aa[8];
#pragma unroll
            for (int ci = 0; ci < 8; ci++) vv[ci] = Vs[jj][tx * 8 + ci];
#pragma unroll
            for (int wj = 0; wj < 8; wj++) aa[wj] = As[jj][ty * 8 + wj];
#pragma unroll
            for (int ci = 0; ci < 8; ci++)
#pragma unroll
                for (int wj = 0; wj < 8; wj++)
                    acc[ci][wj] = fmaf(vv[ci], aa[wj], acc[ci][wj]);
        }
        __syncthreads();
    }
#pragma unroll
    for (int wj = 0; wj < 8; wj++) {
        int w = ty * 8 + wj;
        const ushort4* cp = (const ushort4*)(out_t + (size_t)(h * WW + w) * 512 + c0 + tx * 8);
        ushort4 u0 = cp[0], u1 = cp[1];
        acc[0][wj] += bf2f(u0.x); acc[1][wj] += bf2f(u0.y);
        acc[2][wj] += bf2f(u0.z); acc[3][wj] += bf2f(u0.w);
        acc[4][wj] += bf2f(u1.x); acc[5][wj] += bf2f(u1.y);
        acc[6][wj] += bf2f(u1.z); acc[7][wj] += bf2f(u1.w);
    }
    const float g = ldg<F32>(gamma, 0);
#pragma unroll
    for (int ci = 0; ci < 8; ci++) {
        int c = c0 + tx * 8 + ci;
        size_t base = (size_t)(c * HH + h) * WW + ty * 8;
        float r[8];
#pragma unroll
        for (int k = 0; k < 8; k++)
            r[k] = g * acc[ci][k] + ldg<F32>(x, base + k);
        if (F32) {
            float* op = (float*)out + base;
            ((float4*)op)[0] = make_float4(r[0], r[1], r[2], r[3]);
            ((float4*)op)[1] = make_float4(r[4], r[5], r[6], r[7]);
        } else {
            u16* op = (u16*)out + base;
            ushort4 o0 = { f2bf(r[0]), f2bf(r[1]), f2bf(r[2]), f2bf(r[3]) };
            ushort4 o1 = { f2bf(r[4]), f2bf(r[5]), f2bf(r[6]), f2bf(r[7]) };
            *(ushort4*)(op) = o0;
            *(ushort4*)(op + 4) = o1;
        }
    }
}

__global__ __launch_bounds__(256) void aggB_kernel(
    const u16* v_t, const u16* attn_b, const u16* out_t,
    const void* x_f32, const void* x_b16, const void* gamma,
    const int* __restrict__ dflag, void* out_f32, void* out_b16)
{
    __shared__ float Vs[16][128];
    __shared__ float As[16][132];
    if (*dflag)
        aggB_body<true >(v_t, attn_b, out_t, x_f32, gamma, out_f32, Vs, As);
    else
        aggB_body<false>(v_t, attn_b, out_t, x_b16, gamma, out_b16, Vs, As);
}

// ---------------------------------------------------------------------------
extern "C" void kernel_launch(void* const* d_in, const int* in_sizes, int n_in,
                              void* d_out, int out_size, void* d_ws, size_t ws_size,
                              hipStream_t stream)
{
    const void* x     = d_in[0];
    const void* Wq    = d_in[1];
    const void* bq    = d_in[2];
    const void* Wk    = d_in[3];
    const void* bk    = d_in[4];
    const void* Wv    = d_in[5];
    const void* bv    = d_in[6];
    const void* gamma = d_in[7];

    // workspace (~57.3 MiB peak) with dead-buffer reuse:
    //   dflag | bcat fp32 | W_hi/W_lo bf16 [640][512] | q_t fp32 4MiB |
    //   k_t fp32 4MiB | v_t bf16 16MiB | xT_hi bf16 16MiB | xT_lo bf16 16MiB.
    //   attn_f fp32 16MiB overlays xT_hi (dead after projmm);
    //   attn_b bf16 8MiB overlays q_t+k_t (dead after energies);
    //   out_t bf16 16MiB overlays xT_lo (dead after projmm).
    char* ws = (char*)d_ws;
    int*   dflag = (int*)ws;
    float* bcat  = (float*)(ws + 256);
    size_t off = 4096;
    u16* W_hi = (u16*)(ws + off); off += (size_t)640 * 512 * 2;
    u16* W_lo = (u16*)(ws + off); off += (size_t)640 * 512 * 2;
    float* q_t = (float*)(ws + off); off += (size_t)PP * 64 * 4;
    float* k_t = (float*)(ws + off); off += (size_t)PP * 64 * 4;
    u16* v_t   = (u16*)(ws + off);  off += (size_t)PP * 512 * 2;
    u16* xT_hi = (u16*)(ws + off);  off += (size_t)PP * 512 * 2;
    u16* xT_lo = (u16*)(ws + off);  off += (size_t)PP * 512 * 2;
    float* attn_f = (float*)xT_hi;
    u16*   attn_b = (u16*)q_t;
    u16*   out_t  = (u16*)xT_lo;

    detect_kernel<<<dim3(1), 256, 0, stream>>>(x, dflag);
    wconv_kernel<<<dim3(640), 256, 0, stream>>>(
        Wq, bq, Wk, bk, Wv, bv, dflag, W_hi, W_lo, bcat);

    for (int b = 0; b < BB; b++) {
        const void* x_f = (const void*)((const float*)x + (size_t)b * CC * PP);
        const void* x_h = (const void*)((const u16*)x   + (size_t)b * CC * PP);
        void* o_f = (void*)((float*)d_out + (size_t)b * CC * PP);
        void* o_h = (void*)((u16*)d_out   + (size_t)b * CC * PP);
        trans_kernel<<<dim3(PP / 64, CC / 64), 256, 0, stream>>>(
            x_f, x_h, dflag, xT_hi, xT_lo);
        projmm_kernel<<<dim3(PP / 128, 5), 256, 0, stream>>>(
            xT_hi, xT_lo, W_hi, W_lo, bcat, q_t, k_t, v_t);
        energyH_kernel<<<dim3(WW), 256, 0, stream>>>(q_t, k_t, attn_f);
        energyW_kernel<<<dim3(HH), 256, 0, stream>>>(q_t, k_t, attn_f);
        softmax_kernel<<<dim3(PP / 4), 256, 0, stream>>>(attn_f, attn_b);
        aggA_kernel<<<dim3(4, WW), 256, 0, stream>>>(v_t, attn_b, out_t);
        aggB_kernel<<<dim3(4, HH), 256, 0, stream>>>(
            v_t, attn_b, out_t, x_f, x_h, gamma, dflag, o_f, o_h);
    }
}

// Round 4
// 736.359 us; speedup vs baseline: 2.4445x; 1.1278x over previous
//
#include <hip/hip_runtime.h>
#include <hip/hip_bf16.h>
#include <math.h>

typedef unsigned short u16;

#define BB 4
#define CC 512
#define HH 128
#define WW 128
#define PP (HH*WW)   // 16384 spatial positions per batch

#define NEG_BIG (-3.0e38f)

typedef float f32x4 __attribute__((ext_vector_type(4)));
typedef __bf16 bf16x8 __attribute__((ext_vector_type(8)));

__device__ __forceinline__ float bf2f(u16 u) {
    union { unsigned int i; float f; } v; v.i = ((unsigned int)u) << 16; return v.f;
}
__device__ __forceinline__ u16 f2bf(float f) {
    __hip_bfloat16 h = __float2bfloat16(f);
    u16 u; __builtin_memcpy(&u, &h, 2); return u;
}

template<bool F32>
__device__ __forceinline__ float ldg(const void* p, size_t i) {
    if (F32) return ((const float*)p)[i];
    return bf2f(((const u16*)p)[i]);
}

// async global->LDS, 16B per lane; LDS dest = wave-uniform base + lane*16
__device__ __forceinline__ void gl2lds16(const void* g, void* l) {
    __builtin_amdgcn_global_load_lds(
        (const __attribute__((address_space(1))) unsigned int*)g,
        (__attribute__((address_space(3))) unsigned int*)l,
        16, 0, 0);
}

// ---------------------------------------------------------------------------
// K0: input dtype detection (flag=1 -> fp32).
// ---------------------------------------------------------------------------
__global__ __launch_bounds__(256) void detect_kernel(const void* x, int* flag)
{
    const int t = threadIdx.x;
    const unsigned int* w = (const unsigned int*)x;
    int cnt = 0;
#pragma unroll
    for (int s = 0; s < 16; s++) {
        unsigned int v = w[t * 16 + s];
        int e = (v >> 7) & 0xFF;
        cnt += (e >= 100 && e < 132) ? 1 : 0;
    }
    __shared__ int sh[256];
    sh[t] = cnt;
    __syncthreads();
    for (int o = 128; o; o >>= 1) {
        if (t < o) sh[t] += sh[t + o];
        __syncthreads();
    }
    if (t == 0) *flag = (sh[0] < 2048) ? 1 : 0;
}

// ---------------------------------------------------------------------------
// K0b: weight/bias conversion (once).  [Wq;Wk;Wv] -> [640][512] hi/lo bf16.
// ---------------------------------------------------------------------------
template<bool F32>
__device__ __forceinline__ void wconv_body(
    const void* Wq, const void* bq, const void* Wk, const void* bk,
    const void* Wv, const void* bv,
    u16* __restrict__ Wh, u16* __restrict__ Wl, float* __restrict__ bcat)
{
    const int o = blockIdx.x;
    const int t = threadIdx.x;
#pragma unroll
    for (int s = 0; s < 2; s++) {
        int c = t + s * 256;
        float v;
        if (o < 64)       v = ldg<F32>(Wq, (size_t)o * CC + c);
        else if (o < 128) v = ldg<F32>(Wk, (size_t)(o - 64) * CC + c);
        else              v = ldg<F32>(Wv, (size_t)(o - 128) * CC + c);
        u16 h = f2bf(v);
        Wh[(size_t)o * CC + c] = h;
        Wl[(size_t)o * CC + c] = f2bf(v - bf2f(h));
    }
    if (t == 0) {
        bcat[o] = (o < 64) ? ldg<F32>(bq, o)
                : (o < 128) ? ldg<F32>(bk, o - 64)
                : ldg<F32>(bv, o - 128);
    }
}

__global__ __launch_bounds__(256) void wconv_kernel(
    const void* Wq, const void* bq, const void* Wk, const void* bk,
    const void* Wv, const void* bv, const int* __restrict__ dflag,
    u16* Wh, u16* Wl, float* bcat)
{
    if (*dflag) wconv_body<true >(Wq, bq, Wk, bk, Wv, bv, Wh, Wl, bcat);
    else        wconv_body<false>(Wq, bq, Wk, bk, Wv, bv, Wh, Wl, bcat);
}

// ---------------------------------------------------------------------------
// K0c: per-batch transpose+split: x [512][16384] -> xT_hi/xT_lo [16384][512] bf16.
// ---------------------------------------------------------------------------
template<bool F32>
__device__ __forceinline__ void trans_body(
    const void* __restrict__ x, u16* __restrict__ xh, u16* __restrict__ xl,
    float (*T)[65])
{
    const int t = threadIdx.x;
    const int p0 = blockIdx.x * 64;
    const int c0 = blockIdx.y * 64;
    {
        const int pp = t & 63;
        const int cb = t >> 6;   // 0..3
#pragma unroll
        for (int s = 0; s < 16; s++) {
            int cc = cb * 16 + s;
            T[cc][pp] = ldg<F32>(x, (size_t)(c0 + cc) * PP + p0 + pp);
        }
    }
    __syncthreads();
    {
        const int pr = t >> 2;          // 0..63
        const int cb = (t & 3) * 16;    // 0,16,32,48
        u16 hi[16], lo[16];
#pragma unroll
        for (int j = 0; j < 16; j++) {
            float v = T[cb + j][pr];
            u16 h = f2bf(v);
            hi[j] = h;
            lo[j] = f2bf(v - bf2f(h));
        }
        size_t base = (size_t)(p0 + pr) * 512 + c0 + cb;
#pragma unroll
        for (int s = 0; s < 4; s++) {
            *(ushort4*)(xh + base + s * 4) = *(ushort4*)(hi + s * 4);
            *(ushort4*)(xl + base + s * 4) = *(ushort4*)(lo + s * 4);
        }
    }
}

__global__ __launch_bounds__(256) void trans_kernel(
    const void* x_f32, const void* x_b16, const int* __restrict__ dflag,
    u16* xh, u16* xl)
{
    __shared__ float T[64][65];
    if (*dflag) trans_body<true >(x_f32, xh, xl, T);
    else        trans_body<false>(x_b16, xh, xl, T);
}

// ---------------------------------------------------------------------------
// K1: MFMA split-GEMM projection.
// Tile 0 (o0=0, q/k): K'=1536 (x_hi.W_hi | x_hi.W_lo | x_lo.W_hi) ~ fp32.
// Tiles 1..4 (V): K'=512, single x_hi.W_hi term (bf16 v storage dominates).
// q -> q_t fp32 [p][64]; k -> k_t fp32 [p][64]; v -> v_c bf16 [c][p] (c-major!).
// ---------------------------------------------------------------------------
__global__ __launch_bounds__(256) void projmm_kernel(
    const u16* __restrict__ xT_hi, const u16* __restrict__ xT_lo,
    const u16* __restrict__ W_hi,  const u16* __restrict__ W_lo,
    const float* __restrict__ bcat,
    float* __restrict__ q_t, float* __restrict__ k_t, u16* __restrict__ v_c)
{
    __shared__ __align__(16) u16 Asl[128 * 32];
    __shared__ __align__(16) u16 Bsl[128 * 32];
    const int t = threadIdx.x;
    const int lane = t & 63, wid = t >> 6;
    const int wr = wid >> 1, wc = wid & 1;
    const int fr = lane & 15, fq = lane >> 4;
    const int p0 = blockIdx.x * 128;
    const int o0 = blockIdx.y * 128;
    const int KTOT = (blockIdx.y == 0) ? 1536 : 512;

    f32x4 acc[4][4];
#pragma unroll
    for (int i = 0; i < 4; i++)
#pragma unroll
        for (int j = 0; j < 4; j++) acc[i][j] = (f32x4){0.f, 0.f, 0.f, 0.f};

    const int srow0  = wid * 32 + (lane >> 2);
    const int kchunk = (lane & 3) ^ ((lane >> 2) & 3);
    const size_t gA0 = (size_t)(p0 + srow0) * 512 + kchunk * 8;
    const size_t gA1 = gA0 + (size_t)16 * 512;
    const size_t gB0 = (size_t)(o0 + srow0) * 512 + kchunk * 8;
    const size_t gB1 = gB0 + (size_t)16 * 512;
    u16* ldsA = Asl + wid * 1024;
    u16* ldsB = Bsl + wid * 1024;

    int aoff[4], boff[4];
#pragma unroll
    for (int mi = 0; mi < 4; mi++) {
        int row = wr * 64 + mi * 16 + fr;
        aoff[mi] = row * 32 + ((fq ^ (row & 3)) * 8);
    }
#pragma unroll
    for (int ni = 0; ni < 4; ni++) {
        int row = wc * 64 + ni * 16 + fr;
        boff[ni] = row * 32 + ((fq ^ (row & 3)) * 8);
    }

    for (int k0 = 0; k0 < KTOT; k0 += 32) {
        const int rg = k0 >> 9;          // 0,1,2 (uniform)
        const int kc = k0 & 511;
        const u16* xs   = (rg == 2) ? xT_lo : xT_hi;
        const u16* wsrc = (rg == 1) ? W_lo  : W_hi;
        gl2lds16(xs + gA0 + kc, ldsA);
        gl2lds16(xs + gA1 + kc, ldsA + 512);
        gl2lds16(wsrc + gB0 + kc, ldsB);
        gl2lds16(wsrc + gB1 + kc, ldsB + 512);
        __syncthreads();

        bf16x8 av[4], bv8[4];
#pragma unroll
        for (int mi = 0; mi < 4; mi++) av[mi] = *(const bf16x8*)(Asl + aoff[mi]);
#pragma unroll
        for (int ni = 0; ni < 4; ni++) bv8[ni] = *(const bf16x8*)(Bsl + boff[ni]);
#pragma unroll
        for (int mi = 0; mi < 4; mi++)
#pragma unroll
            for (int ni = 0; ni < 4; ni++)
                acc[mi][ni] = __builtin_amdgcn_mfma_f32_16x16x32_bf16(
                    av[mi], bv8[ni], acc[mi][ni], 0, 0, 0);
        __syncthreads();
    }

    // epilogue: row p = p0+wr*64+mi*16+fq*4+r, col o = o0+wc*64+ni*16+fr
#pragma unroll
    for (int ni = 0; ni < 4; ni++) {
        const int o = o0 + wc * 64 + ni * 16 + fr;
        const float bb = bcat[o];
        if (o < 64) {
#pragma unroll
            for (int mi = 0; mi < 4; mi++) {
                const int pb = p0 + wr * 64 + mi * 16 + fq * 4;
#pragma unroll
                for (int r = 0; r < 4; r++)
                    q_t[(size_t)(pb + r) * 64 + o] = acc[mi][ni][r] + bb;
            }
        } else if (o < 128) {
#pragma unroll
            for (int mi = 0; mi < 4; mi++) {
                const int pb = p0 + wr * 64 + mi * 16 + fq * 4;
#pragma unroll
                for (int r = 0; r < 4; r++)
                    k_t[(size_t)(pb + r) * 64 + (o - 64)] = acc[mi][ni][r] + bb;
            }
        } else {
            const int ch = o - 128;
#pragma unroll
            for (int mi = 0; mi < 4; mi++) {
                const int pb = p0 + wr * 64 + mi * 16 + fq * 4;
                ushort4 u = { f2bf(acc[mi][ni][0] + bb), f2bf(acc[mi][ni][1] + bb),
                              f2bf(acc[mi][ni][2] + bb), f2bf(acc[mi][ni][3] + bb) };
                *(ushort4*)(v_c + (size_t)ch * PP + pb) = u;
            }
        }
    }
}

// ---------------------------------------------------------------------------
// K1b: v spatial transpose: v_a[c][w*128+h] = v_c[c][h*128+w].
// Runs AFTER softmax so v_a can overlay the dead attn_f region.
// ---------------------------------------------------------------------------
__global__ __launch_bounds__(256) void vtrans_kernel(
    const u16* __restrict__ v_c, u16* __restrict__ v_a)
{
    const int c  = blockIdx.x;
    const int w0 = blockIdx.y * 64;
    const int t  = threadIdx.x;
    __shared__ __align__(16) u16 T[64 * 132];   // [wl][h], pad 132
#pragma unroll
    for (int s = 0; s < 4; s++) {
        const int h  = (t >> 3) + s * 32;
        const int wl = (t & 7) * 8;
        const u16* src = v_c + (size_t)c * PP + h * 128 + w0 + wl;
        ushort4 a0 = *(const ushort4*)(src);
        ushort4 a1 = *(const ushort4*)(src + 4);
        T[(wl + 0) * 132 + h] = a0.x; T[(wl + 1) * 132 + h] = a0.y;
        T[(wl + 2) * 132 + h] = a0.z; T[(wl + 3) * 132 + h] = a0.w;
        T[(wl + 4) * 132 + h] = a1.x; T[(wl + 5) * 132 + h] = a1.y;
        T[(wl + 6) * 132 + h] = a1.z; T[(wl + 7) * 132 + h] = a1.w;
    }
    __syncthreads();
#pragma unroll
    for (int s = 0; s < 4; s++) {
        const int wl = (t >> 4) + s * 16;
        const int hh = (t & 15) * 8;
        ushort4 b0 = *(const ushort4*)(T + wl * 132 + hh);
        ushort4 b1 = *(const ushort4*)(T + wl * 132 + hh + 4);
        ushort4* dp = (ushort4*)(v_a + (size_t)c * PP + (size_t)(w0 + wl) * 128 + hh);
        dp[0] = b0; dp[1] = b1;
    }
}

// ---------------------------------------------------------------------------
// shared 128x128(K=128) bf16 MFMA core: A rows stride sA, B rows stride sB,
// k contiguous, chunk-XOR swizzled LDS, global_load_lds staging.
// ---------------------------------------------------------------------------
__device__ __forceinline__ void mm128_core(
    const u16* __restrict__ baseA, size_t sA,
    const u16* __restrict__ baseB, size_t sB,
    u16* Asl, u16* Bsl, int lane, int wid,
    const int* aoff, const int* boff, f32x4 (*acc)[4])
{
    const int srow = wid * 32 + (lane >> 2);
    const int kch  = (lane & 3) ^ ((lane >> 2) & 3);
    const u16* gA = baseA + (size_t)srow * sA + kch * 8;
    const u16* gB = baseB + (size_t)srow * sB + kch * 8;
    u16* ldsA = Asl + wid * 1024;
    u16* ldsB = Bsl + wid * 1024;
    for (int k0 = 0; k0 < 128; k0 += 32) {
        gl2lds16(gA + k0,           ldsA);
        gl2lds16(gA + 16 * sA + k0, ldsA + 512);
        gl2lds16(gB + k0,           ldsB);
        gl2lds16(gB + 16 * sB + k0, ldsB + 512);
        __syncthreads();
        bf16x8 av[4], bv8[4];
#pragma unroll
        for (int mi = 0; mi < 4; mi++) av[mi] = *(const bf16x8*)(Asl + aoff[mi]);
#pragma unroll
        for (int ni = 0; ni < 4; ni++) bv8[ni] = *(const bf16x8*)(Bsl + boff[ni]);
#pragma unroll
        for (int mi = 0; mi < 4; mi++)
#pragma unroll
            for (int ni = 0; ni < 4; ni++)
                acc[mi][ni] = __builtin_amdgcn_mfma_f32_16x16x32_bf16(
                    av[mi], bv8[ni], acc[mi][ni], 0, 0, 0);
        __syncthreads();
    }
}

#define FRAG_OFFS(arr, wq)                                      \
    int arr[4];                                                 \
    _Pragma("unroll")                                           \
    for (int ii = 0; ii < 4; ii++) {                            \
        int row = (wq) * 64 + ii * 16 + fr;                     \
        arr[ii] = row * 32 + ((fq ^ (row & 3)) * 8);            \
    }

// ---------------------------------------------------------------------------
// K5: aggA (MFMA).  Per (c-tile, w): D[h][c] = sum_i attnH[h,w,i] * v_a[c][w*128+i]
// out_t[(h*128+w)*512 + c] bf16 via LDS re-coalesce (256B rows).
// ---------------------------------------------------------------------------
__global__ __launch_bounds__(256) void aggA_mm_kernel(
    const u16* __restrict__ v_a, const u16* __restrict__ attn_b,
    u16* __restrict__ out_t)
{
    __shared__ __align__(16) u16 Asl[128 * 32];
    __shared__ __align__(16) u16 Bsl[128 * 32];
    __shared__ __align__(16) u16 Dst[128 * 132];
    const int t = threadIdx.x;
    const int lane = t & 63, wid = t >> 6;
    const int wr = wid >> 1, wc = wid & 1;
    const int fr = lane & 15, fq = lane >> 4;
    const int c0 = blockIdx.x * 128;
    const int w  = blockIdx.y;

    f32x4 acc[4][4];
#pragma unroll
    for (int i = 0; i < 4; i++)
#pragma unroll
        for (int j = 0; j < 4; j++) acc[i][j] = (f32x4){0.f, 0.f, 0.f, 0.f};

    FRAG_OFFS(aoff, wr)
    FRAG_OFFS(boff, wc)

    // A: rows h, stride 128*256 elems; base attn_b + w*256 (H-half of row)
    // B: rows c, stride PP; base v_a + c0*PP + w*128
    mm128_core(attn_b + (size_t)w * 256, (size_t)128 * 256,
               v_a + (size_t)c0 * PP + (size_t)w * 128, (size_t)PP,
               Asl, Bsl, lane, wid, aoff, boff, acc);

    // stage D[h][c] -> Dst (bf16), then coalesced 256B-row writes
#pragma unroll
    for (int mi = 0; mi < 4; mi++)
#pragma unroll
        for (int ni = 0; ni < 4; ni++) {
            const int c = wc * 64 + ni * 16 + fr;
#pragma unroll
            for (int r = 0; r < 4; r++) {
                const int h = wr * 64 + mi * 16 + fq * 4 + r;
                Dst[h * 132 + c] = f2bf(acc[mi][ni][r]);
            }
        }
    __syncthreads();
#pragma unroll
    for (int s = 0; s < 8; s++) {
        const int h = s * 16 + (t >> 4);
        const int c = (t & 15) * 8;
        ushort4 a0 = *(const ushort4*)(Dst + h * 132 + c);
        ushort4 a1 = *(const ushort4*)(Dst + h * 132 + c + 4);
        ushort4* dp = (ushort4*)(out_t + (size_t)(h * WW + w) * 512 + c0 + c);
        dp[0] = a0; dp[1] = a1;
    }
}

// ---------------------------------------------------------------------------
// K6: aggB (MFMA) + fused epilogue.  Per (c-tile, h):
//   D[w][c] = sum_j attnW[h,w,j] * v_c[c][h*128+j]
//   out[c][h][w] = gamma*(D + out_t) + x   (x/out pre-offset per batch)
// ---------------------------------------------------------------------------
template<bool F32>
__device__ __forceinline__ void aggB_mm_body(
    const u16* __restrict__ v_c, const u16* __restrict__ attn_b,
    const u16* __restrict__ out_t, const void* __restrict__ x,
    const void* __restrict__ gamma, void* __restrict__ out,
    u16* Asl, u16* Bsl, char* epi)
{
    const int t = threadIdx.x;
    const int lane = t & 63, wid = t >> 6;
    const int wr = wid >> 1, wc = wid & 1;
    const int fr = lane & 15, fq = lane >> 4;
    const int c0 = blockIdx.x * 128;
    const int h  = blockIdx.y;

    f32x4 acc[4][4];
#pragma unroll
    for (int i = 0; i < 4; i++)
#pragma unroll
        for (int j = 0; j < 4; j++) acc[i][j] = (f32x4){0.f, 0.f, 0.f, 0.f};

    FRAG_OFFS(aoff, wr)
    FRAG_OFFS(boff, wc)

    // A: rows w, stride 256, base attn_b + h*128*256 + 128 (W-half)
    // B: rows c, stride PP, base v_c + c0*PP + h*128
    mm128_core(attn_b + (size_t)h * 128 * 256 + 128, (size_t)256,
               v_c + (size_t)c0 * PP + (size_t)h * 128, (size_t)PP,
               Asl, Bsl, lane, wid, aoff, boff, acc);

    // 1) stage out_t tile -> OAs[w][c] (pad 136), coalesced reads
    u16* OAs = (u16*)epi;
#pragma unroll
    for (int s = 0; s < 8; s++) {
        const int wrow = s * 16 + (t >> 4);
        const int c = (t & 15) * 8;
        const u16* sp = out_t + (size_t)(h * WW + wrow) * 512 + c0 + c;
        ushort4 a0 = *(const ushort4*)(sp);
        ushort4 a1 = *(const ushort4*)(sp + 4);
        *(ushort4*)(OAs + wrow * 136 + c)     = a0;
        *(ushort4*)(OAs + wrow * 136 + c + 4) = a1;
    }
    __syncthreads();
    // 2) acc += OA
#pragma unroll
    for (int mi = 0; mi < 4; mi++)
#pragma unroll
        for (int ni = 0; ni < 4; ni++) {
            const int c = wc * 64 + ni * 16 + fr;
#pragma unroll
            for (int r = 0; r < 4; r++) {
                const int ww = wr * 64 + mi * 16 + fq * 4 + r;
                acc[mi][ni][r] += bf2f(OAs[ww * 136 + c]);
            }
        }
    __syncthreads();   // OAs consumed; reuse as DstF

    const float g = ldg<F32>(gamma, 0);
    float* DstF = (float*)epi;       // [64][132] fp32
#pragma unroll
    for (int half = 0; half < 2; half++) {
        if (wc == half) {
#pragma unroll
            for (int mi = 0; mi < 4; mi++)
#pragma unroll
                for (int ni = 0; ni < 4; ni++) {
                    const int cl = ni * 16 + fr;
                    const int w0 = wr * 64 + mi * 16 + fq * 4;
                    f32x4 vv = acc[mi][ni];
                    *(f32x4*)(DstF + cl * 132 + w0) = vv;
                }
        }
        __syncthreads();
#pragma unroll
        for (int s = 0; s < 8; s++) {
            const int e  = s * 1024 + t * 4;
            const int cl = e >> 7;
            const int wq = e & 127;
            f32x4 vv = *(const f32x4*)(DstF + cl * 132 + wq);
            const size_t base = (size_t)(c0 + half * 64 + cl) * PP + h * 128 + wq;
            float r0 = g * vv[0] + ldg<F32>(x, base + 0);
            float r1 = g * vv[1] + ldg<F32>(x, base + 1);
            float r2 = g * vv[2] + ldg<F32>(x, base + 2);
            float r3 = g * vv[3] + ldg<F32>(x, base + 3);
            if (F32) {
                *(float4*)((float*)out + base) = make_float4(r0, r1, r2, r3);
            } else {
                ushort4 o = { f2bf(r0), f2bf(r1), f2bf(r2), f2bf(r3) };
                *(ushort4*)((u16*)out + base) = o;
            }
        }
        __syncthreads();
    }
}

__global__ __launch_bounds__(256) void aggB_mm_kernel(
    const u16* v_c, const u16* attn_b, const u16* out_t,
    const void* x_f32, const void* x_b16, const void* gamma,
    const int* __restrict__ dflag, void* out_f32, void* out_b16)
{
    __shared__ __align__(16) u16 Asl[128 * 32];
    __shared__ __align__(16) u16 Bsl[128 * 32];
    __shared__ __align__(16) char epi[128 * 136 * 2];  // OAs u16[128][136] / DstF f32[64][132]
    if (*dflag)
        aggB_mm_body<true >(v_c, attn_b, out_t, x_f32, gamma, out_f32, Asl, Bsl, epi);
    else
        aggB_mm_body<false>(v_c, attn_b, out_t, x_b16, gamma, out_b16, Asl, Bsl, epi);
}

// ---------------------------------------------------------------------------
// K2: energy_H.  Block per w: E[h][i] = sum_c q[h,w,c]*k[i,w,c]; diag -> NEG_BIG.
// ---------------------------------------------------------------------------
__global__ __launch_bounds__(256) void energyH_kernel(
    const float* __restrict__ q_t, const float* __restrict__ k_t,
    float* __restrict__ attn_f)
{
    const int w = blockIdx.x;
    const int t = threadIdx.x, tx = t & 15, ty = t >> 4;
    __shared__ float Qs[32][128];
    __shared__ float Ks[32][128];
    float acc[8][8];
#pragma unroll
    for (int i = 0; i < 8; i++)
#pragma unroll
        for (int j = 0; j < 8; j++) acc[i][j] = 0.f;

    for (int cb = 0; cb < 2; cb++) {
        const int hh = t >> 1;
        const int cl0 = (t & 1) * 16;
        const int cg0 = cb * 32 + cl0;
        const float4* q4 = (const float4*)(q_t + (size_t)(hh * WW + w) * 64 + cg0);
        const float4* k4 = (const float4*)(k_t + (size_t)(hh * WW + w) * 64 + cg0);
#pragma unroll
        for (int s = 0; s < 4; s++) {
            float4 qv = q4[s], kv = k4[s];
            int c = cl0 + s * 4;
            Qs[c][hh] = qv.x; Qs[c + 1][hh] = qv.y; Qs[c + 2][hh] = qv.z; Qs[c + 3][hh] = qv.w;
            Ks[c][hh] = kv.x; Ks[c + 1][hh] = kv.y; Ks[c + 2][hh] = kv.z; Ks[c + 3][hh] = kv.w;
        }
        __syncthreads();
#pragma unroll 4
        for (int c = 0; c < 32; c++) {
            float a[8], bb[8];
#pragma unroll
            for (int i = 0; i < 8; i++) a[i] = Qs[c][ty * 8 + i];
#pragma unroll
            for (int j = 0; j < 8; j++) bb[j] = Ks[c][tx * 8 + j];
#pragma unroll
            for (int i = 0; i < 8; i++)
#pragma unroll
                for (int j = 0; j < 8; j++)
                    acc[i][j] = fmaf(a[i], bb[j], acc[i][j]);
        }
        __syncthreads();
    }
#pragma unroll
    for (int i = 0; i < 8; i++) {
        int h = ty * 8 + i;
        float* row = attn_f + (size_t)(h * WW + w) * 256;
        float v[8];
#pragma unroll
        for (int j = 0; j < 8; j++) {
            int ic = tx * 8 + j;
            v[j] = (ic == h) ? NEG_BIG : acc[i][j];
        }
        ((float4*)(row + tx * 8))[0] = make_float4(v[0], v[1], v[2], v[3]);
        ((float4*)(row + tx * 8))[1] = make_float4(v[4], v[5], v[6], v[7]);
    }
}

// ---------------------------------------------------------------------------
// K3: energy_W.  Block per h: E[w][j] = sum_c q[h,w,c]*k[h,j,c].
// ---------------------------------------------------------------------------
__global__ __launch_bounds__(256) void energyW_kernel(
    const float* __restrict__ q_t, const float* __restrict__ k_t,
    float* __restrict__ attn_f)
{
    const int h = blockIdx.x;
    const int t = threadIdx.x, tx = t & 15, ty = t >> 4;
    __shared__ float Qs[32][128];
    __shared__ float Ks[32][128];
    float acc[8][8];
#pragma unroll
    for (int i = 0; i < 8; i++)
#pragma unroll
        for (int j = 0; j < 8; j++) acc[i][j] = 0.f;

    for (int cb = 0; cb < 2; cb++) {
        const int ww = t >> 1;
        const int cl0 = (t & 1) * 16;
        const int cg0 = cb * 32 + cl0;
        const float4* q4 = (const float4*)(q_t + (size_t)(h * WW + ww) * 64 + cg0);
        const float4* k4 = (const float4*)(k_t + (size_t)(h * WW + ww) * 64 + cg0);
#pragma unroll
        for (int s = 0; s < 4; s++) {
            float4 qv = q4[s], kv = k4[s];
            int c = cl0 + s * 4;
            Qs[c][ww] = qv.x; Qs[c + 1][ww] = qv.y; Qs[c + 2][ww] = qv.z; Qs[c + 3][ww] = qv.w;
            Ks[c][ww] = kv.x; Ks[c + 1][ww] = kv.y; Ks[c + 2][ww] = kv.z; Ks[c + 3][ww] = kv.w;
        }
        __syncthreads();
#pragma unroll 4
        for (int c = 0; c < 32; c++) {
            float a[8], bb[8];
#pragma unroll
            for (int i = 0; i < 8; i++) a[i] = Qs[c][ty * 8 + i];
#pragma unroll
            for (int j = 0; j < 8; j++) bb[j] = Ks[c][tx * 8 + j];
#pragma unroll
            for (int i = 0; i < 8; i++)
#pragma unroll
                for (int j = 0; j < 8; j++)
                    acc[i][j] = fmaf(a[i], bb[j], acc[i][j]);
        }
        __syncthreads();
    }
#pragma unroll
    for (int i = 0; i < 8; i++) {
        int w = ty * 8 + i;
        float* row = attn_f + (size_t)(h * WW + w) * 256 + 128;
        ((float4*)(row + tx * 8))[0] = make_float4(acc[i][0], acc[i][1], acc[i][2], acc[i][3]);
        ((float4*)(row + tx * 8))[1] = make_float4(acc[i][4], acc[i][5], acc[i][6], acc[i][7]);
    }
}

// ---------------------------------------------------------------------------
// K4: softmax over 256, one wave per row, fp32 -> bf16, finite-guarded.
// ---------------------------------------------------------------------------
__global__ __launch_bounds__(256) void softmax_kernel(
    const float* __restrict__ attn_f, u16* __restrict__ attn_b)
{
    const int wave = threadIdx.x >> 6, lane = threadIdx.x & 63;
    const size_t row = (size_t)blockIdx.x * 4 + wave;
    const float* rp = attn_f + row * 256;
    float4 v = ((const float4*)rp)[lane];
    v.x = isfinite(v.x) ? v.x : NEG_BIG;
    v.y = isfinite(v.y) ? v.y : NEG_BIG;
    v.z = isfinite(v.z) ? v.z : NEG_BIG;
    v.w = isfinite(v.w) ? v.w : NEG_BIG;
    float m = fmaxf(fmaxf(v.x, v.y), fmaxf(v.z, v.w));
#pragma unroll
    for (int off = 32; off; off >>= 1) m = fmaxf(m, __shfl_xor(m, off));
    float e0 = __expf(v.x - m), e1 = __expf(v.y - m);
    float e2 = __expf(v.z - m), e3 = __expf(v.w - m);
    float s = e0 + e1 + e2 + e3;
#pragma unroll
    for (int off = 32; off; off >>= 1) s += __shfl_xor(s, off);
    float inv = 1.0f / s;
    ushort4 u = { f2bf(e0 * inv), f2bf(e1 * inv), f2bf(e2 * inv), f2bf(e3 * inv) };
    ((ushort4*)(attn_b + row * 256))[lane] = u;
}

// ---------------------------------------------------------------------------
extern "C" void kernel_launch(void* const* d_in, const int* in_sizes, int n_in,
                              void* d_out, int out_size, void* d_ws, size_t ws_size,
                              hipStream_t stream)
{
    const void* x     = d_in[0];
    const void* Wq    = d_in[1];
    const void* bq    = d_in[2];
    const void* Wk    = d_in[3];
    const void* bk    = d_in[4];
    const void* Wv    = d_in[5];
    const void* bv    = d_in[6];
    const void* gamma = d_in[7];

    // workspace (~57.3 MiB peak — same as the proven round-1 footprint):
    //   dflag | bcat | W_hi/W_lo bf16 | q_t fp32 4MiB | k_t fp32 4MiB |
    //   v_c bf16 [c][p] 16MiB | xT_hi 16MiB | xT_lo 16MiB.
    // Overlays (per-batch order: trans, projmm, eH, eW, softmax, vtrans, aggA, aggB):
    //   attn_f fp32 16MiB = xT_hi (xT_hi dead after projmm)
    //   v_a    bf16 16MiB = xT_hi (attn_f dead after softmax; vtrans runs after)
    //   attn_b bf16  8MiB = q_t+k_t (dead after energies)
    //   out_t  bf16 16MiB = xT_lo (dead after projmm)
    char* ws = (char*)d_ws;
    int*   dflag = (int*)ws;
    float* bcat  = (float*)(ws + 256);
    size_t off = 4096;
    u16* W_hi = (u16*)(ws + off); off += (size_t)640 * 512 * 2;
    u16* W_lo = (u16*)(ws + off); off += (size_t)640 * 512 * 2;
    float* q_t = (float*)(ws + off); off += (size_t)PP * 64 * 4;
    float* k_t = (float*)(ws + off); off += (size_t)PP * 64 * 4;
    u16* v_c   = (u16*)(ws + off);  off += (size_t)PP * 512 * 2;
    u16* xT_hi = (u16*)(ws + off);  off += (size_t)PP * 512 * 2;
    u16* xT_lo = (u16*)(ws + off);  off += (size_t)PP * 512 * 2;
    float* attn_f = (float*)xT_hi;
    u16*   v_a    = (u16*)xT_hi;
    u16*   attn_b = (u16*)q_t;
    u16*   out_t  = (u16*)xT_lo;

    detect_kernel<<<dim3(1), 256, 0, stream>>>(x, dflag);
    wconv_kernel<<<dim3(640), 256, 0, stream>>>(
        Wq, bq, Wk, bk, Wv, bv, dflag, W_hi, W_lo, bcat);

    for (int b = 0; b < BB; b++) {
        const void* x_f = (const void*)((const float*)x + (size_t)b * CC * PP);
        const void* x_h = (const void*)((const u16*)x   + (size_t)b * CC * PP);
        void* o_f = (void*)((float*)d_out + (size_t)b * CC * PP);
        void* o_h = (void*)((u16*)d_out   + (size_t)b * CC * PP);
        trans_kernel<<<dim3(PP / 64, CC / 64), 256, 0, stream>>>(
            x_f, x_h, dflag, xT_hi, xT_lo);
        projmm_kernel<<<dim3(PP / 128, 5), 256, 0, stream>>>(
            xT_hi, xT_lo, W_hi, W_lo, bcat, q_t, k_t, v_c);
        energyH_kernel<<<dim3(WW), 256, 0, stream>>>(q_t, k_t, attn_f);
        energyW_kernel<<<dim3(HH), 256, 0, stream>>>(q_t, k_t, attn_f);
        softmax_kernel<<<dim3(PP / 4), 256, 0, stream>>>(attn_f, attn_b);
        vtrans_kernel<<<dim3(CC, 2), 256, 0, stream>>>(v_c, v_a);
        aggA_mm_kernel<<<dim3(4, WW), 256, 0, stream>>>(v_a, attn_b, out_t);
        aggB_mm_kernel<<<dim3(4, HH), 256, 0, stream>>>(
            v_c, attn_b, out_t, x_f, x_h, gamma, dflag, o_f, o_h);
    }
}

// Round 5
// 673.641 us; speedup vs baseline: 2.6721x; 1.0931x over previous
//
#include <hip/hip_runtime.h>
#include <hip/hip_bf16.h>
#include <math.h>

typedef unsigned short u16;

#define BB 4
#define CC 512
#define HH 128
#define WW 128
#define PP (HH*WW)   // 16384 spatial positions per batch

#define NEG_BIG (-3.0e38f)

typedef float f32x4 __attribute__((ext_vector_type(4)));
typedef __bf16 bf16x8 __attribute__((ext_vector_type(8)));

__device__ __forceinline__ float bf2f(u16 u) {
    union { unsigned int i; float f; } v; v.i = ((unsigned int)u) << 16; return v.f;
}
__device__ __forceinline__ u16 f2bf(float f) {
    __hip_bfloat16 h = __float2bfloat16(f);
    u16 u; __builtin_memcpy(&u, &h, 2); return u;
}

template<bool F32>
__device__ __forceinline__ float ldg(const void* p, size_t i) {
    if (F32) return ((const float*)p)[i];
    return bf2f(((const u16*)p)[i]);
}

// async global->LDS, 16B per lane; LDS dest = wave-uniform base + lane*16
__device__ __forceinline__ void gl2lds16(const void* g, void* l) {
    __builtin_amdgcn_global_load_lds(
        (const __attribute__((address_space(1))) unsigned int*)g,
        (__attribute__((address_space(3))) unsigned int*)l,
        16, 0, 0);
}

// ---------------------------------------------------------------------------
// K0: input dtype detection (flag=1 -> fp32).
// ---------------------------------------------------------------------------
__global__ __launch_bounds__(256) void detect_kernel(const void* x, int* flag)
{
    const int t = threadIdx.x;
    const unsigned int* w = (const unsigned int*)x;
    int cnt = 0;
#pragma unroll
    for (int s = 0; s < 16; s++) {
        unsigned int v = w[t * 16 + s];
        int e = (v >> 7) & 0xFF;
        cnt += (e >= 100 && e < 132) ? 1 : 0;
    }
    __shared__ int sh[256];
    sh[t] = cnt;
    __syncthreads();
    for (int o = 128; o; o >>= 1) {
        if (t < o) sh[t] += sh[t + o];
        __syncthreads();
    }
    if (t == 0) *flag = (sh[0] < 2048) ? 1 : 0;
}

// ---------------------------------------------------------------------------
// K0b: weight/bias conversion (once).  [Wq;Wk;Wv] -> [640][512] hi/lo bf16.
// ---------------------------------------------------------------------------
template<bool F32>
__device__ __forceinline__ void wconv_body(
    const void* Wq, const void* bq, const void* Wk, const void* bk,
    const void* Wv, const void* bv,
    u16* __restrict__ Wh, u16* __restrict__ Wl, float* __restrict__ bcat)
{
    const int o = blockIdx.x;
    const int t = threadIdx.x;
#pragma unroll
    for (int s = 0; s < 2; s++) {
        int c = t + s * 256;
        float v;
        if (o < 64)       v = ldg<F32>(Wq, (size_t)o * CC + c);
        else if (o < 128) v = ldg<F32>(Wk, (size_t)(o - 64) * CC + c);
        else              v = ldg<F32>(Wv, (size_t)(o - 128) * CC + c);
        u16 h = f2bf(v);
        Wh[(size_t)o * CC + c] = h;
        Wl[(size_t)o * CC + c] = f2bf(v - bf2f(h));
    }
    if (t == 0) {
        bcat[o] = (o < 64) ? ldg<F32>(bq, o)
                : (o < 128) ? ldg<F32>(bk, o - 64)
                : ldg<F32>(bv, o - 128);
    }
}

__global__ __launch_bounds__(256) void wconv_kernel(
    const void* Wq, const void* bq, const void* Wk, const void* bk,
    const void* Wv, const void* bv, const int* __restrict__ dflag,
    u16* Wh, u16* Wl, float* bcat)
{
    if (*dflag) wconv_body<true >(Wq, bq, Wk, bk, Wv, bv, Wh, Wl, bcat);
    else        wconv_body<false>(Wq, bq, Wk, bk, Wv, bv, Wh, Wl, bcat);
}

// ---------------------------------------------------------------------------
// K0c: per-batch transpose+split: x [512][16384] -> xT_hi/xT_lo [16384][512] bf16.
// ---------------------------------------------------------------------------
template<bool F32>
__device__ __forceinline__ void trans_body(
    const void* __restrict__ x, u16* __restrict__ xh, u16* __restrict__ xl,
    float (*T)[65])
{
    const int t = threadIdx.x;
    const int p0 = blockIdx.x * 64;
    const int c0 = blockIdx.y * 64;
    {
        const int pp = t & 63;
        const int cb = t >> 6;   // 0..3
#pragma unroll
        for (int s = 0; s < 16; s++) {
            int cc = cb * 16 + s;
            T[cc][pp] = ldg<F32>(x, (size_t)(c0 + cc) * PP + p0 + pp);
        }
    }
    __syncthreads();
    {
        const int pr = t >> 2;          // 0..63
        const int cb = (t & 3) * 16;    // 0,16,32,48
        u16 hi[16], lo[16];
#pragma unroll
        for (int j = 0; j < 16; j++) {
            float v = T[cb + j][pr];
            u16 h = f2bf(v);
            hi[j] = h;
            lo[j] = f2bf(v - bf2f(h));
        }
        size_t base = (size_t)(p0 + pr) * 512 + c0 + cb;
#pragma unroll
        for (int s = 0; s < 4; s++) {
            *(ushort4*)(xh + base + s * 4) = *(ushort4*)(hi + s * 4);
            *(ushort4*)(xl + base + s * 4) = *(ushort4*)(lo + s * 4);
        }
    }
}

__global__ __launch_bounds__(256) void trans_kernel(
    const void* x_f32, const void* x_b16, const int* __restrict__ dflag,
    u16* xh, u16* xl)
{
    __shared__ float T[64][65];
    if (*dflag) trans_body<true >(x_f32, xh, xl, T);
    else        trans_body<false>(x_b16, xh, xl, T);
}

// ---------------------------------------------------------------------------
// K1: MFMA split-GEMM projection.
// Tile 0 (o0=0, q/k): K'=1536 (x_hi.W_hi | x_hi.W_lo | x_lo.W_hi) ~ fp32.
// Tiles 1..4 (V): K'=512, single x_hi.W_hi term (bf16 v storage dominates).
// q -> q2 bf16 [p][128] = [q_hi|q_lo]; k -> k2 likewise; v -> v_c bf16 [c][p].
// ---------------------------------------------------------------------------
__global__ __launch_bounds__(256) void projmm_kernel(
    const u16* __restrict__ xT_hi, const u16* __restrict__ xT_lo,
    const u16* __restrict__ W_hi,  const u16* __restrict__ W_lo,
    const float* __restrict__ bcat,
    u16* __restrict__ q2, u16* __restrict__ k2, u16* __restrict__ v_c)
{
    __shared__ __align__(16) u16 Asl[128 * 32];
    __shared__ __align__(16) u16 Bsl[128 * 32];
    const int t = threadIdx.x;
    const int lane = t & 63, wid = t >> 6;
    const int wr = wid >> 1, wc = wid & 1;
    const int fr = lane & 15, fq = lane >> 4;
    const int p0 = blockIdx.x * 128;
    const int o0 = blockIdx.y * 128;
    const int KTOT = (blockIdx.y == 0) ? 1536 : 512;

    f32x4 acc[4][4];
#pragma unroll
    for (int i = 0; i < 4; i++)
#pragma unroll
        for (int j = 0; j < 4; j++) acc[i][j] = (f32x4){0.f, 0.f, 0.f, 0.f};

    const int srow0  = wid * 32 + (lane >> 2);
    const int kchunk = (lane & 3) ^ ((lane >> 2) & 3);
    const size_t gA0 = (size_t)(p0 + srow0) * 512 + kchunk * 8;
    const size_t gA1 = gA0 + (size_t)16 * 512;
    const size_t gB0 = (size_t)(o0 + srow0) * 512 + kchunk * 8;
    const size_t gB1 = gB0 + (size_t)16 * 512;
    u16* ldsA = Asl + wid * 1024;
    u16* ldsB = Bsl + wid * 1024;

    int aoff[4], boff[4];
#pragma unroll
    for (int mi = 0; mi < 4; mi++) {
        int row = wr * 64 + mi * 16 + fr;
        aoff[mi] = row * 32 + ((fq ^ (row & 3)) * 8);
    }
#pragma unroll
    for (int ni = 0; ni < 4; ni++) {
        int row = wc * 64 + ni * 16 + fr;
        boff[ni] = row * 32 + ((fq ^ (row & 3)) * 8);
    }

    for (int k0 = 0; k0 < KTOT; k0 += 32) {
        const int rg = k0 >> 9;          // 0,1,2 (uniform)
        const int kc = k0 & 511;
        const u16* xs   = (rg == 2) ? xT_lo : xT_hi;
        const u16* wsrc = (rg == 1) ? W_lo  : W_hi;
        gl2lds16(xs + gA0 + kc, ldsA);
        gl2lds16(xs + gA1 + kc, ldsA + 512);
        gl2lds16(wsrc + gB0 + kc, ldsB);
        gl2lds16(wsrc + gB1 + kc, ldsB + 512);
        __syncthreads();

        bf16x8 av[4], bv8[4];
#pragma unroll
        for (int mi = 0; mi < 4; mi++) av[mi] = *(const bf16x8*)(Asl + aoff[mi]);
#pragma unroll
        for (int ni = 0; ni < 4; ni++) bv8[ni] = *(const bf16x8*)(Bsl + boff[ni]);
#pragma unroll
        for (int mi = 0; mi < 4; mi++)
#pragma unroll
            for (int ni = 0; ni < 4; ni++)
                acc[mi][ni] = __builtin_amdgcn_mfma_f32_16x16x32_bf16(
                    av[mi], bv8[ni], acc[mi][ni], 0, 0, 0);
        __syncthreads();
    }

    // epilogue: row p = p0+wr*64+mi*16+fq*4+r, col o = o0+wc*64+ni*16+fr
#pragma unroll
    for (int ni = 0; ni < 4; ni++) {
        const int o = o0 + wc * 64 + ni * 16 + fr;
        const float bb = bcat[o];
        if (o < 64) {
#pragma unroll
            for (int mi = 0; mi < 4; mi++) {
                const int pb = p0 + wr * 64 + mi * 16 + fq * 4;
#pragma unroll
                for (int r = 0; r < 4; r++) {
                    float val = acc[mi][ni][r] + bb;
                    u16 hi = f2bf(val);
                    q2[(size_t)(pb + r) * 128 + o]      = hi;
                    q2[(size_t)(pb + r) * 128 + 64 + o] = f2bf(val - bf2f(hi));
                }
            }
        } else if (o < 128) {
            const int oc = o - 64;
#pragma unroll
            for (int mi = 0; mi < 4; mi++) {
                const int pb = p0 + wr * 64 + mi * 16 + fq * 4;
#pragma unroll
                for (int r = 0; r < 4; r++) {
                    float val = acc[mi][ni][r] + bb;
                    u16 hi = f2bf(val);
                    k2[(size_t)(pb + r) * 128 + oc]      = hi;
                    k2[(size_t)(pb + r) * 128 + 64 + oc] = f2bf(val - bf2f(hi));
                }
            }
        } else {
            const int ch = o - 128;
#pragma unroll
            for (int mi = 0; mi < 4; mi++) {
                const int pb = p0 + wr * 64 + mi * 16 + fq * 4;
                ushort4 u = { f2bf(acc[mi][ni][0] + bb), f2bf(acc[mi][ni][1] + bb),
                              f2bf(acc[mi][ni][2] + bb), f2bf(acc[mi][ni][3] + bb) };
                *(ushort4*)(v_c + (size_t)ch * PP + pb) = u;
            }
        }
    }
}

// ---------------------------------------------------------------------------
// K1b: v spatial transpose: v_a[c][w*128+h] = v_c[c][h*128+w].
// Runs AFTER softmax so v_a can overlay the dead attn_f region.
// ---------------------------------------------------------------------------
__global__ __launch_bounds__(256) void vtrans_kernel(
    const u16* __restrict__ v_c, u16* __restrict__ v_a)
{
    const int c  = blockIdx.x;
    const int w0 = blockIdx.y * 64;
    const int t  = threadIdx.x;
    __shared__ __align__(16) u16 T[64 * 132];   // [wl][h], pad 132
#pragma unroll
    for (int s = 0; s < 4; s++) {
        const int h  = (t >> 3) + s * 32;
        const int wl = (t & 7) * 8;
        const u16* src = v_c + (size_t)c * PP + h * 128 + w0 + wl;
        ushort4 a0 = *(const ushort4*)(src);
        ushort4 a1 = *(const ushort4*)(src + 4);
        T[(wl + 0) * 132 + h] = a0.x; T[(wl + 1) * 132 + h] = a0.y;
        T[(wl + 2) * 132 + h] = a0.z; T[(wl + 3) * 132 + h] = a0.w;
        T[(wl + 4) * 132 + h] = a1.x; T[(wl + 5) * 132 + h] = a1.y;
        T[(wl + 6) * 132 + h] = a1.z; T[(wl + 7) * 132 + h] = a1.w;
    }
    __syncthreads();
#pragma unroll
    for (int s = 0; s < 4; s++) {
        const int wl = (t >> 4) + s * 16;
        const int hh = (t & 15) * 8;
        ushort4 b0 = *(const ushort4*)(T + wl * 132 + hh);
        ushort4 b1 = *(const ushort4*)(T + wl * 132 + hh + 4);
        ushort4* dp = (ushort4*)(v_a + (size_t)c * PP + (size_t)(w0 + wl) * 128 + hh);
        dp[0] = b0; dp[1] = b1;
    }
}

// ---------------------------------------------------------------------------
// shared 128x128(K=128) bf16 MFMA core: A rows stride sA, B rows stride sB,
// k contiguous, chunk-XOR swizzled LDS, global_load_lds staging.
// ---------------------------------------------------------------------------
__device__ __forceinline__ void mm128_core(
    const u16* __restrict__ baseA, size_t sA,
    const u16* __restrict__ baseB, size_t sB,
    u16* Asl, u16* Bsl, int lane, int wid,
    const int* aoff, const int* boff, f32x4 (*acc)[4])
{
    const int srow = wid * 32 + (lane >> 2);
    const int kch  = (lane & 3) ^ ((lane >> 2) & 3);
    const u16* gA = baseA + (size_t)srow * sA + kch * 8;
    const u16* gB = baseB + (size_t)srow * sB + kch * 8;
    u16* ldsA = Asl + wid * 1024;
    u16* ldsB = Bsl + wid * 1024;
    for (int k0 = 0; k0 < 128; k0 += 32) {
        gl2lds16(gA + k0,           ldsA);
        gl2lds16(gA + 16 * sA + k0, ldsA + 512);
        gl2lds16(gB + k0,           ldsB);
        gl2lds16(gB + 16 * sB + k0, ldsB + 512);
        __syncthreads();
        bf16x8 av[4], bv8[4];
#pragma unroll
        for (int mi = 0; mi < 4; mi++) av[mi] = *(const bf16x8*)(Asl + aoff[mi]);
#pragma unroll
        for (int ni = 0; ni < 4; ni++) bv8[ni] = *(const bf16x8*)(Bsl + boff[ni]);
#pragma unroll
        for (int mi = 0; mi < 4; mi++)
#pragma unroll
            for (int ni = 0; ni < 4; ni++)
                acc[mi][ni] = __builtin_amdgcn_mfma_f32_16x16x32_bf16(
                    av[mi], bv8[ni], acc[mi][ni], 0, 0, 0);
        __syncthreads();
    }
}

#define FRAG_OFFS(arr, wq)                                      \
    int arr[4];                                                 \
    _Pragma("unroll")                                           \
    for (int ii = 0; ii < 4; ii++) {                            \
        int row = (wq) * 64 + ii * 16 + fr;                     \
        arr[ii] = row * 32 + ((fq ^ (row & 3)) * 8);            \
    }

// ---------------------------------------------------------------------------
// K2: fused energy (MFMA, fp32-equivalent via hi/lo 3-term split).
// grid (128, 2): y=0 -> energy_H at w=blockIdx.x (rows h, stride 16384);
//                y=1 -> energy_W at h=blockIdx.x (rows w, stride 128).
// E = q_hi.k_hi + q_hi.k_lo + q_lo.k_hi  (6 K-steps of 32, slice-selected).
// ---------------------------------------------------------------------------
__global__ __launch_bounds__(256) void energy_mm_kernel(
    const u16* __restrict__ q2, const u16* __restrict__ k2,
    float* __restrict__ attn_f)
{
    __shared__ __align__(16) u16 Asl[128 * 32];
    __shared__ __align__(16) u16 Bsl[128 * 32];
    const int t = threadIdx.x;
    const int lane = t & 63, wid = t >> 6;
    const int wr = wid >> 1, wc = wid & 1;
    const int fr = lane & 15, fq = lane >> 4;
    const int isW = blockIdx.y;              // uniform
    const int fx  = blockIdx.x;

    const size_t sA   = isW ? 128 : (size_t)128 * 128;
    const size_t base = isW ? (size_t)fx * 128 * 128 : (size_t)fx * 128;

    f32x4 acc[4][4];
#pragma unroll
    for (int i = 0; i < 4; i++)
#pragma unroll
        for (int j = 0; j < 4; j++) acc[i][j] = (f32x4){0.f, 0.f, 0.f, 0.f};

    const int srow = wid * 32 + (lane >> 2);
    const int kch  = (lane & 3) ^ ((lane >> 2) & 3);
    const u16* gA = q2 + base + (size_t)srow * sA + kch * 8;
    const u16* gB = k2 + base + (size_t)srow * sA + kch * 8;
    u16* ldsA = Asl + wid * 1024;
    u16* ldsB = Bsl + wid * 1024;

    FRAG_OFFS(aoff, wr)
    FRAG_OFFS(boff, wc)

    const int AK[6] = {0, 32, 0, 32, 64, 96};   // q: hi hi hi hi lo lo
    const int BK[6] = {0, 32, 64, 96, 0, 32};   // k: hi hi lo lo hi hi
#pragma unroll
    for (int s = 0; s < 6; s++) {
        gl2lds16(gA + AK[s],           ldsA);
        gl2lds16(gA + 16 * sA + AK[s], ldsA + 512);
        gl2lds16(gB + BK[s],           ldsB);
        gl2lds16(gB + 16 * sA + BK[s], ldsB + 512);
        __syncthreads();
        bf16x8 av[4], bv8[4];
#pragma unroll
        for (int mi = 0; mi < 4; mi++) av[mi] = *(const bf16x8*)(Asl + aoff[mi]);
#pragma unroll
        for (int ni = 0; ni < 4; ni++) bv8[ni] = *(const bf16x8*)(Bsl + boff[ni]);
#pragma unroll
        for (int mi = 0; mi < 4; mi++)
#pragma unroll
            for (int ni = 0; ni < 4; ni++)
                acc[mi][ni] = __builtin_amdgcn_mfma_f32_16x16x32_bf16(
                    av[mi], bv8[ni], acc[mi][ni], 0, 0, 0);
        __syncthreads();
    }

    // epilogue: M index rm (h for eH, w for eW); N index cn (i or j)
#pragma unroll
    for (int ni = 0; ni < 4; ni++) {
        const int cn = wc * 64 + ni * 16 + fr;
#pragma unroll
        for (int mi = 0; mi < 4; mi++) {
            const int rm0 = wr * 64 + mi * 16 + fq * 4;
#pragma unroll
            for (int r = 0; r < 4; r++) {
                const int rm = rm0 + r;
                const size_t prow = isW ? ((size_t)fx * 128 + rm)
                                        : ((size_t)rm * 128 + fx);
                float vv = acc[mi][ni][r];
                if (!isW && cn == rm) vv = NEG_BIG;
                attn_f[prow * 256 + (size_t)isW * 128 + cn] = vv;
            }
        }
    }
}

// ---------------------------------------------------------------------------
// K5: aggA (MFMA).  Per (c-tile, w): D[h][c] = sum_i attnH[h,w,i] * v_a[c][w*128+i]
// out_t[(h*128+w)*512 + c] bf16 via LDS re-coalesce (256B rows).
// ---------------------------------------------------------------------------
__global__ __launch_bounds__(256) void aggA_mm_kernel(
    const u16* __restrict__ v_a, const u16* __restrict__ attn_b,
    u16* __restrict__ out_t)
{
    __shared__ __align__(16) u16 Asl[128 * 32];
    __shared__ __align__(16) u16 Bsl[128 * 32];
    __shared__ __align__(16) u16 Dst[128 * 132];
    const int t = threadIdx.x;
    const int lane = t & 63, wid = t >> 6;
    const int wr = wid >> 1, wc = wid & 1;
    const int fr = lane & 15, fq = lane >> 4;
    const int c0 = blockIdx.x * 128;
    const int w  = blockIdx.y;

    f32x4 acc[4][4];
#pragma unroll
    for (int i = 0; i < 4; i++)
#pragma unroll
        for (int j = 0; j < 4; j++) acc[i][j] = (f32x4){0.f, 0.f, 0.f, 0.f};

    FRAG_OFFS(aoff, wr)
    FRAG_OFFS(boff, wc)

    // A: rows h, stride 128*256 elems; base attn_b + w*256 (H-half of row)
    // B: rows c, stride PP; base v_a + c0*PP + w*128
    mm128_core(attn_b + (size_t)w * 256, (size_t)128 * 256,
               v_a + (size_t)c0 * PP + (size_t)w * 128, (size_t)PP,
               Asl, Bsl, lane, wid, aoff, boff, acc);

    // stage D[h][c] -> Dst (bf16), then coalesced 256B-row writes
#pragma unroll
    for (int mi = 0; mi < 4; mi++)
#pragma unroll
        for (int ni = 0; ni < 4; ni++) {
            const int c = wc * 64 + ni * 16 + fr;
#pragma unroll
            for (int r = 0; r < 4; r++) {
                const int h = wr * 64 + mi * 16 + fq * 4 + r;
                Dst[h * 132 + c] = f2bf(acc[mi][ni][r]);
            }
        }
    __syncthreads();
#pragma unroll
    for (int s = 0; s < 8; s++) {
        const int h = s * 16 + (t >> 4);
        const int c = (t & 15) * 8;
        ushort4 a0 = *(const ushort4*)(Dst + h * 132 + c);
        ushort4 a1 = *(const ushort4*)(Dst + h * 132 + c + 4);
        ushort4* dp = (ushort4*)(out_t + (size_t)(h * WW + w) * 512 + c0 + c);
        dp[0] = a0; dp[1] = a1;
    }
}

// ---------------------------------------------------------------------------
// K6: aggB (MFMA) + fused epilogue.  Per (c-tile, h):
//   D[w][c] = sum_j attnW[h,w,j] * v_c[c][h*128+j]
//   out[c][h][w] = gamma*(D + out_t) + x   (x/out pre-offset per batch)
// ---------------------------------------------------------------------------
template<bool F32>
__device__ __forceinline__ void aggB_mm_body(
    const u16* __restrict__ v_c, const u16* __restrict__ attn_b,
    const u16* __restrict__ out_t, const void* __restrict__ x,
    const void* __restrict__ gamma, void* __restrict__ out,
    u16* Asl, u16* Bsl, char* epi)
{
    const int t = threadIdx.x;
    const int lane = t & 63, wid = t >> 6;
    const int wr = wid >> 1, wc = wid & 1;
    const int fr = lane & 15, fq = lane >> 4;
    const int c0 = blockIdx.x * 128;
    const int h  = blockIdx.y;

    f32x4 acc[4][4];
#pragma unroll
    for (int i = 0; i < 4; i++)
#pragma unroll
        for (int j = 0; j < 4; j++) acc[i][j] = (f32x4){0.f, 0.f, 0.f, 0.f};

    FRAG_OFFS(aoff, wr)
    FRAG_OFFS(boff, wc)

    // A: rows w, stride 256, base attn_b + h*128*256 + 128 (W-half)
    // B: rows c, stride PP, base v_c + c0*PP + h*128
    mm128_core(attn_b + (size_t)h * 128 * 256 + 128, (size_t)256,
               v_c + (size_t)c0 * PP + (size_t)h * 128, (size_t)PP,
               Asl, Bsl, lane, wid, aoff, boff, acc);

    // 1) stage out_t tile -> OAs[w][c] (pad 136), coalesced reads
    u16* OAs = (u16*)epi;
#pragma unroll
    for (int s = 0; s < 8; s++) {
        const int wrow = s * 16 + (t >> 4);
        const int c = (t & 15) * 8;
        const u16* sp = out_t + (size_t)(h * WW + wrow) * 512 + c0 + c;
        ushort4 a0 = *(const ushort4*)(sp);
        ushort4 a1 = *(const ushort4*)(sp + 4);
        *(ushort4*)(OAs + wrow * 136 + c)     = a0;
        *(ushort4*)(OAs + wrow * 136 + c + 4) = a1;
    }
    __syncthreads();
    // 2) acc += OA
#pragma unroll
    for (int mi = 0; mi < 4; mi++)
#pragma unroll
        for (int ni = 0; ni < 4; ni++) {
            const int c = wc * 64 + ni * 16 + fr;
#pragma unroll
            for (int r = 0; r < 4; r++) {
                const int ww = wr * 64 + mi * 16 + fq * 4 + r;
                acc[mi][ni][r] += bf2f(OAs[ww * 136 + c]);
            }
        }
    __syncthreads();   // OAs consumed; reuse as DstF

    const float g = ldg<F32>(gamma, 0);
    float* DstF = (float*)epi;       // [64][132] fp32
#pragma unroll
    for (int half = 0; half < 2; half++) {
        if (wc == half) {
#pragma unroll
            for (int mi = 0; mi < 4; mi++)
#pragma unroll
                for (int ni = 0; ni < 4; ni++) {
                    const int cl = ni * 16 + fr;
                    const int w0 = wr * 64 + mi * 16 + fq * 4;
                    f32x4 vv = acc[mi][ni];
                    *(f32x4*)(DstF + cl * 132 + w0) = vv;
                }
        }
        __syncthreads();
#pragma unroll
        for (int s = 0; s < 8; s++) {
            const int e  = s * 1024 + t * 4;
            const int cl = e >> 7;
            const int wq = e & 127;
            f32x4 vv = *(const f32x4*)(DstF + cl * 132 + wq);
            const size_t base = (size_t)(c0 + half * 64 + cl) * PP + h * 128 + wq;
            float r0 = g * vv[0] + ldg<F32>(x, base + 0);
            float r1 = g * vv[1] + ldg<F32>(x, base + 1);
            float r2 = g * vv[2] + ldg<F32>(x, base + 2);
            float r3 = g * vv[3] + ldg<F32>(x, base + 3);
            if (F32) {
                *(float4*)((float*)out + base) = make_float4(r0, r1, r2, r3);
            } else {
                ushort4 o = { f2bf(r0), f2bf(r1), f2bf(r2), f2bf(r3) };
                *(ushort4*)((u16*)out + base) = o;
            }
        }
        __syncthreads();
    }
}

__global__ __launch_bounds__(256) void aggB_mm_kernel(
    const u16* v_c, const u16* attn_b, const u16* out_t,
    const void* x_f32, const void* x_b16, const void* gamma,
    const int* __restrict__ dflag, void* out_f32, void* out_b16)
{
    __shared__ __align__(16) u16 Asl[128 * 32];
    __shared__ __align__(16) u16 Bsl[128 * 32];
    __shared__ __align__(16) char epi[128 * 136 * 2];  // OAs u16[128][136] / DstF f32[64][132]
    if (*dflag)
        aggB_mm_body<true >(v_c, attn_b, out_t, x_f32, gamma, out_f32, Asl, Bsl, epi);
    else
        aggB_mm_body<false>(v_c, attn_b, out_t, x_b16, gamma, out_b16, Asl, Bsl, epi);
}

// ---------------------------------------------------------------------------
// K4: softmax over 256, one wave per row, fp32 -> bf16, finite-guarded.
// ---------------------------------------------------------------------------
__global__ __launch_bounds__(256) void softmax_kernel(
    const float* __restrict__ attn_f, u16* __restrict__ attn_b)
{
    const int wave = threadIdx.x >> 6, lane = threadIdx.x & 63;
    const size_t row = (size_t)blockIdx.x * 4 + wave;
    const float* rp = attn_f + row * 256;
    float4 v = ((const float4*)rp)[lane];
    v.x = isfinite(v.x) ? v.x : NEG_BIG;
    v.y = isfinite(v.y) ? v.y : NEG_BIG;
    v.z = isfinite(v.z) ? v.z : NEG_BIG;
    v.w = isfinite(v.w) ? v.w : NEG_BIG;
    float m = fmaxf(fmaxf(v.x, v.y), fmaxf(v.z, v.w));
#pragma unroll
    for (int off = 32; off; off >>= 1) m = fmaxf(m, __shfl_xor(m, off));
    float e0 = __expf(v.x - m), e1 = __expf(v.y - m);
    float e2 = __expf(v.z - m), e3 = __expf(v.w - m);
    float s = e0 + e1 + e2 + e3;
#pragma unroll
    for (int off = 32; off; off >>= 1) s += __shfl_xor(s, off);
    float inv = 1.0f / s;
    ushort4 u = { f2bf(e0 * inv), f2bf(e1 * inv), f2bf(e2 * inv), f2bf(e3 * inv) };
    ((ushort4*)(attn_b + row * 256))[lane] = u;
}

// ---------------------------------------------------------------------------
extern "C" void kernel_launch(void* const* d_in, const int* in_sizes, int n_in,
                              void* d_out, int out_size, void* d_ws, size_t ws_size,
                              hipStream_t stream)
{
    const void* x     = d_in[0];
    const void* Wq    = d_in[1];
    const void* bq    = d_in[2];
    const void* Wk    = d_in[3];
    const void* bk    = d_in[4];
    const void* Wv    = d_in[5];
    const void* bv    = d_in[6];
    const void* gamma = d_in[7];

    // workspace (~57.3 MiB peak — same as the proven round-1/4 footprint):
    //   dflag | bcat | W_hi/W_lo bf16 | q2 bf16 [p][128] 4MiB | k2 4MiB |
    //   v_c bf16 [c][p] 16MiB | xT_hi 16MiB | xT_lo 16MiB.
    // Overlays (order: trans, projmm, energy, softmax, vtrans, aggA, aggB):
    //   attn_f fp32 16MiB = xT_hi (xT_hi dead after projmm)
    //   v_a    bf16 16MiB = xT_hi (attn_f dead after softmax)
    //   attn_b bf16  8MiB = q2+k2 (dead after energy)
    //   out_t  bf16 16MiB = xT_lo (dead after projmm)
    char* ws = (char*)d_ws;
    int*   dflag = (int*)ws;
    float* bcat  = (float*)(ws + 256);
    size_t off = 4096;
    u16* W_hi = (u16*)(ws + off); off += (size_t)640 * 512 * 2;
    u16* W_lo = (u16*)(ws + off); off += (size_t)640 * 512 * 2;
    u16* q2   = (u16*)(ws + off); off += (size_t)PP * 128 * 2;
    u16* k2   = (u16*)(ws + off); off += (size_t)PP * 128 * 2;
    u16* v_c   = (u16*)(ws + off);  off += (size_t)PP * 512 * 2;
    u16* xT_hi = (u16*)(ws + off);  off += (size_t)PP * 512 * 2;
    u16* xT_lo = (u16*)(ws + off);  off += (size_t)PP * 512 * 2;
    float* attn_f = (float*)xT_hi;
    u16*   v_a    = (u16*)xT_hi;
    u16*   attn_b = (u16*)q2;
    u16*   out_t  = (u16*)xT_lo;

    detect_kernel<<<dim3(1), 256, 0, stream>>>(x, dflag);
    wconv_kernel<<<dim3(640), 256, 0, stream>>>(
        Wq, bq, Wk, bk, Wv, bv, dflag, W_hi, W_lo, bcat);

    for (int b = 0; b < BB; b++) {
        const void* x_f = (const void*)((const float*)x + (size_t)b * CC * PP);
        const void* x_h = (const void*)((const u16*)x   + (size_t)b * CC * PP);
        void* o_f = (void*)((float*)d_out + (size_t)b * CC * PP);
        void* o_h = (void*)((u16*)d_out   + (size_t)b * CC * PP);
        trans_kernel<<<dim3(PP / 64, CC / 64), 256, 0, stream>>>(
            x_f, x_h, dflag, xT_hi, xT_lo);
        projmm_kernel<<<dim3(PP / 128, 5), 256, 0, stream>>>(
            xT_hi, xT_lo, W_hi, W_lo, bcat, q2, k2, v_c);
        energy_mm_kernel<<<dim3(128, 2), 256, 0, stream>>>(q2, k2, attn_f);
        softmax_kernel<<<dim3(PP / 4), 256, 0, stream>>>(attn_f, attn_b);
        vtrans_kernel<<<dim3(CC, 2), 256, 0, stream>>>(v_c, v_a);
        aggA_mm_kernel<<<dim3(4, WW), 256, 0, stream>>>(v_a, attn_b, out_t);
        aggB_mm_kernel<<<dim3(4, HH), 256, 0, stream>>>(
            v_c, attn_b, out_t, x_f, x_h, gamma, dflag, o_f, o_h);
    }
}

// Round 6
// 650.374 us; speedup vs baseline: 2.7677x; 1.0358x over previous
//
#include <hip/hip_runtime.h>
#include <hip/hip_bf16.h>
#include <math.h>

typedef unsigned short u16;

#define BB 4
#define CC 512
#define HH 128
#define WW 128
#define PP (HH*WW)   // 16384 spatial positions per batch

#define NEG_BIG (-3.0e38f)

typedef float f32x4 __attribute__((ext_vector_type(4)));
typedef __bf16 bf16x8 __attribute__((ext_vector_type(8)));

__device__ __forceinline__ float bf2f(u16 u) {
    union { unsigned int i; float f; } v; v.i = ((unsigned int)u) << 16; return v.f;
}
__device__ __forceinline__ u16 f2bf(float f) {
    __hip_bfloat16 h = __float2bfloat16(f);
    u16 u; __builtin_memcpy(&u, &h, 2); return u;
}

template<bool F32>
__device__ __forceinline__ float ldg(const void* p, size_t i) {
    if (F32) return ((const float*)p)[i];
    return bf2f(((const u16*)p)[i]);
}

// async global->LDS, 16B per lane; LDS dest = wave-uniform base + lane*16
__device__ __forceinline__ void gl2lds16(const void* g, void* l) {
    __builtin_amdgcn_global_load_lds(
        (const __attribute__((address_space(1))) unsigned int*)g,
        (__attribute__((address_space(3))) unsigned int*)l,
        16, 0, 0);
}

// ---------------------------------------------------------------------------
// K0: input dtype detection (flag=1 -> fp32).
// ---------------------------------------------------------------------------
__global__ __launch_bounds__(256) void detect_kernel(const void* x, int* flag)
{
    const int t = threadIdx.x;
    const unsigned int* w = (const unsigned int*)x;
    int cnt = 0;
#pragma unroll
    for (int s = 0; s < 16; s++) {
        unsigned int v = w[t * 16 + s];
        int e = (v >> 7) & 0xFF;
        cnt += (e >= 100 && e < 132) ? 1 : 0;
    }
    __shared__ int sh[256];
    sh[t] = cnt;
    __syncthreads();
    for (int o = 128; o; o >>= 1) {
        if (t < o) sh[t] += sh[t + o];
        __syncthreads();
    }
    if (t == 0) *flag = (sh[0] < 2048) ? 1 : 0;
}

// ---------------------------------------------------------------------------
// K0b: weight/bias conversion (once).  [Wq;Wk;Wv] -> [640][512] hi/lo bf16.
// ---------------------------------------------------------------------------
template<bool F32>
__device__ __forceinline__ void wconv_body(
    const void* Wq, const void* bq, const void* Wk, const void* bk,
    const void* Wv, const void* bv,
    u16* __restrict__ Wh, u16* __restrict__ Wl, float* __restrict__ bcat)
{
    const int o = blockIdx.x;
    const int t = threadIdx.x;
#pragma unroll
    for (int s = 0; s < 2; s++) {
        int c = t + s * 256;
        float v;
        if (o < 64)       v = ldg<F32>(Wq, (size_t)o * CC + c);
        else if (o < 128) v = ldg<F32>(Wk, (size_t)(o - 64) * CC + c);
        else              v = ldg<F32>(Wv, (size_t)(o - 128) * CC + c);
        u16 h = f2bf(v);
        Wh[(size_t)o * CC + c] = h;
        Wl[(size_t)o * CC + c] = f2bf(v - bf2f(h));
    }
    if (t == 0) {
        bcat[o] = (o < 64) ? ldg<F32>(bq, o)
                : (o < 128) ? ldg<F32>(bk, o - 64)
                : ldg<F32>(bv, o - 128);
    }
}

__global__ __launch_bounds__(256) void wconv_kernel(
    const void* Wq, const void* bq, const void* Wk, const void* bk,
    const void* Wv, const void* bv, const int* __restrict__ dflag,
    u16* Wh, u16* Wl, float* bcat)
{
    if (*dflag) wconv_body<true >(Wq, bq, Wk, bk, Wv, bv, Wh, Wl, bcat);
    else        wconv_body<false>(Wq, bq, Wk, bk, Wv, bv, Wh, Wl, bcat);
}

// ---------------------------------------------------------------------------
// K0c: per-batch transpose+split: x [512][16384] -> xT_hi/xT_lo [16384][512] bf16.
// ---------------------------------------------------------------------------
template<bool F32>
__device__ __forceinline__ void trans_body(
    const void* __restrict__ x, u16* __restrict__ xh, u16* __restrict__ xl,
    float (*T)[65])
{
    const int t = threadIdx.x;
    const int p0 = blockIdx.x * 64;
    const int c0 = blockIdx.y * 64;
    {
        const int pp = t & 63;
        const int cb = t >> 6;   // 0..3
#pragma unroll
        for (int s = 0; s < 16; s++) {
            int cc = cb * 16 + s;
            T[cc][pp] = ldg<F32>(x, (size_t)(c0 + cc) * PP + p0 + pp);
        }
    }
    __syncthreads();
    {
        const int pr = t >> 2;          // 0..63
        const int cb = (t & 3) * 16;    // 0,16,32,48
        u16 hi[16], lo[16];
#pragma unroll
        for (int j = 0; j < 16; j++) {
            float v = T[cb + j][pr];
            u16 h = f2bf(v);
            hi[j] = h;
            lo[j] = f2bf(v - bf2f(h));
        }
        size_t base = (size_t)(p0 + pr) * 512 + c0 + cb;
#pragma unroll
        for (int s = 0; s < 4; s++) {
            *(ushort4*)(xh + base + s * 4) = *(ushort4*)(hi + s * 4);
            *(ushort4*)(xl + base + s * 4) = *(ushort4*)(lo + s * 4);
        }
    }
}

__global__ __launch_bounds__(256) void trans_kernel(
    const void* x_f32, const void* x_b16, const int* __restrict__ dflag,
    u16* xh, u16* xl)
{
    __shared__ float T[64][65];
    if (*dflag) trans_body<true >(x_f32, xh, xl, T);
    else        trans_body<false>(x_b16, xh, xl, T);
}

// ---------------------------------------------------------------------------
// 8-wave MFMA family: 512 threads = 2x4 waves; wave (wr,wc) owns a 64x32
// sub-tile of the 128x128 output; acc[4][2] of f32x4.  Each wave stages ONE
// 16-row x 32-k chunk per operand per K-step (chunk-XOR swizzle both sides).
// Read-offset formula row*32 + ((fq^(row&3))*8) is wave-count-independent.
// ---------------------------------------------------------------------------
#define FRAG_OFFS_A(arr)                                        \
    int arr[4];                                                 \
    _Pragma("unroll")                                           \
    for (int ii = 0; ii < 4; ii++) {                            \
        int row = wr * 64 + ii * 16 + fr;                       \
        arr[ii] = row * 32 + ((fq ^ (row & 3)) * 8);            \
    }
#define FRAG_OFFS_B(arr)                                        \
    int arr[2];                                                 \
    _Pragma("unroll")                                           \
    for (int ii = 0; ii < 2; ii++) {                            \
        int row = wc * 32 + ii * 16 + fr;                       \
        arr[ii] = row * 32 + ((fq ^ (row & 3)) * 8);            \
    }

// ---------------------------------------------------------------------------
// K1: MFMA split-GEMM projection (8-wave).
// Tile 0 (o0=0, q/k): K'=1536 (x_hi.W_hi | x_hi.W_lo | x_lo.W_hi) ~ fp32.
// Tiles 1..4 (V): K'=512, single x_hi.W_hi term (bf16 v storage dominates).
// q -> q2 bf16 [p][128] = [q_hi|q_lo]; k -> k2 likewise; v -> v_c bf16 [c][p].
// ---------------------------------------------------------------------------
__global__ __launch_bounds__(512) void projmm_kernel(
    const u16* __restrict__ xT_hi, const u16* __restrict__ xT_lo,
    const u16* __restrict__ W_hi,  const u16* __restrict__ W_lo,
    const float* __restrict__ bcat,
    u16* __restrict__ q2, u16* __restrict__ k2, u16* __restrict__ v_c)
{
    __shared__ __align__(16) u16 Asl[128 * 32];
    __shared__ __align__(16) u16 Bsl[128 * 32];
    const int t = threadIdx.x;
    const int lane = t & 63, wid = t >> 6;      // wid 0..7
    const int wr = wid >> 2, wc = wid & 3;
    const int fr = lane & 15, fq = lane >> 4;
    const int p0 = blockIdx.x * 128;
    const int o0 = blockIdx.y * 128;
    const int KTOT = (blockIdx.y == 0) ? 1536 : 512;

    f32x4 acc[4][2];
#pragma unroll
    for (int i = 0; i < 4; i++)
#pragma unroll
        for (int j = 0; j < 2; j++) acc[i][j] = (f32x4){0.f, 0.f, 0.f, 0.f};

    const int srow = wid * 16 + (lane >> 2);    // 0..127
    const int kch  = (lane & 3) ^ ((lane >> 2) & 3);
    const size_t gA0 = (size_t)(p0 + srow) * 512 + kch * 8;
    const size_t gB0 = (size_t)(o0 + srow) * 512 + kch * 8;
    u16* ldsA = Asl + wid * 512;
    u16* ldsB = Bsl + wid * 512;

    FRAG_OFFS_A(aoff)
    FRAG_OFFS_B(boff)

    for (int k0 = 0; k0 < KTOT; k0 += 32) {
        const int rg = k0 >> 9;          // 0,1,2 (uniform)
        const int kc = k0 & 511;
        const u16* xs   = (rg == 2) ? xT_lo : xT_hi;
        const u16* wsrc = (rg == 1) ? W_lo  : W_hi;
        gl2lds16(xs + gA0 + kc, ldsA);
        gl2lds16(wsrc + gB0 + kc, ldsB);
        __syncthreads();

        bf16x8 av[4], bv2[2];
#pragma unroll
        for (int mi = 0; mi < 4; mi++) av[mi] = *(const bf16x8*)(Asl + aoff[mi]);
#pragma unroll
        for (int ni = 0; ni < 2; ni++) bv2[ni] = *(const bf16x8*)(Bsl + boff[ni]);
#pragma unroll
        for (int mi = 0; mi < 4; mi++)
#pragma unroll
            for (int ni = 0; ni < 2; ni++)
                acc[mi][ni] = __builtin_amdgcn_mfma_f32_16x16x32_bf16(
                    av[mi], bv2[ni], acc[mi][ni], 0, 0, 0);
        __syncthreads();
    }

    // epilogue: row p = p0+wr*64+mi*16+fq*4+r, col o = o0+wc*32+ni*16+fr
#pragma unroll
    for (int ni = 0; ni < 2; ni++) {
        const int o = o0 + wc * 32 + ni * 16 + fr;
        const float bb = bcat[o];
        if (o < 64) {
#pragma unroll
            for (int mi = 0; mi < 4; mi++) {
                const int pb = p0 + wr * 64 + mi * 16 + fq * 4;
#pragma unroll
                for (int r = 0; r < 4; r++) {
                    float val = acc[mi][ni][r] + bb;
                    u16 hi = f2bf(val);
                    q2[(size_t)(pb + r) * 128 + o]      = hi;
                    q2[(size_t)(pb + r) * 128 + 64 + o] = f2bf(val - bf2f(hi));
                }
            }
        } else if (o < 128) {
            const int oc = o - 64;
#pragma unroll
            for (int mi = 0; mi < 4; mi++) {
                const int pb = p0 + wr * 64 + mi * 16 + fq * 4;
#pragma unroll
                for (int r = 0; r < 4; r++) {
                    float val = acc[mi][ni][r] + bb;
                    u16 hi = f2bf(val);
                    k2[(size_t)(pb + r) * 128 + oc]      = hi;
                    k2[(size_t)(pb + r) * 128 + 64 + oc] = f2bf(val - bf2f(hi));
                }
            }
        } else {
            const int ch = o - 128;
#pragma unroll
            for (int mi = 0; mi < 4; mi++) {
                const int pb = p0 + wr * 64 + mi * 16 + fq * 4;
                ushort4 u = { f2bf(acc[mi][ni][0] + bb), f2bf(acc[mi][ni][1] + bb),
                              f2bf(acc[mi][ni][2] + bb), f2bf(acc[mi][ni][3] + bb) };
                *(ushort4*)(v_c + (size_t)ch * PP + pb) = u;
            }
        }
    }
}

// ---------------------------------------------------------------------------
// K1b: v spatial transpose: v_a[c][w*128+h] = v_c[c][h*128+w].
// Runs AFTER softmax so v_a can overlay the dead attn_f region.
// ---------------------------------------------------------------------------
__global__ __launch_bounds__(256) void vtrans_kernel(
    const u16* __restrict__ v_c, u16* __restrict__ v_a)
{
    const int c  = blockIdx.x;
    const int w0 = blockIdx.y * 64;
    const int t  = threadIdx.x;
    __shared__ __align__(16) u16 T[64 * 132];   // [wl][h], pad 132
#pragma unroll
    for (int s = 0; s < 4; s++) {
        const int h  = (t >> 3) + s * 32;
        const int wl = (t & 7) * 8;
        const u16* src = v_c + (size_t)c * PP + h * 128 + w0 + wl;
        ushort4 a0 = *(const ushort4*)(src);
        ushort4 a1 = *(const ushort4*)(src + 4);
        T[(wl + 0) * 132 + h] = a0.x; T[(wl + 1) * 132 + h] = a0.y;
        T[(wl + 2) * 132 + h] = a0.z; T[(wl + 3) * 132 + h] = a0.w;
        T[(wl + 4) * 132 + h] = a1.x; T[(wl + 5) * 132 + h] = a1.y;
        T[(wl + 6) * 132 + h] = a1.z; T[(wl + 7) * 132 + h] = a1.w;
    }
    __syncthreads();
#pragma unroll
    for (int s = 0; s < 4; s++) {
        const int wl = (t >> 4) + s * 16;
        const int hh = (t & 15) * 8;
        ushort4 b0 = *(const ushort4*)(T + wl * 132 + hh);
        ushort4 b1 = *(const ushort4*)(T + wl * 132 + hh + 4);
        ushort4* dp = (ushort4*)(v_a + (size_t)c * PP + (size_t)(w0 + wl) * 128 + hh);
        dp[0] = b0; dp[1] = b1;
    }
}

// ---------------------------------------------------------------------------
// shared 128x128(K=128) bf16 MFMA core, 8-wave variant.
// ---------------------------------------------------------------------------
__device__ __forceinline__ void mm128_core8(
    const u16* __restrict__ baseA, size_t sA,
    const u16* __restrict__ baseB, size_t sB,
    u16* Asl, u16* Bsl, int lane, int wid,
    const int* aoff, const int* boff, f32x4 (*acc)[2])
{
    const int srow = wid * 16 + (lane >> 2);
    const int kch  = (lane & 3) ^ ((lane >> 2) & 3);
    const u16* gA = baseA + (size_t)srow * sA + kch * 8;
    const u16* gB = baseB + (size_t)srow * sB + kch * 8;
    u16* ldsA = Asl + wid * 512;
    u16* ldsB = Bsl + wid * 512;
    for (int k0 = 0; k0 < 128; k0 += 32) {
        gl2lds16(gA + k0, ldsA);
        gl2lds16(gB + k0, ldsB);
        __syncthreads();
        bf16x8 av[4], bv2[2];
#pragma unroll
        for (int mi = 0; mi < 4; mi++) av[mi] = *(const bf16x8*)(Asl + aoff[mi]);
#pragma unroll
        for (int ni = 0; ni < 2; ni++) bv2[ni] = *(const bf16x8*)(Bsl + boff[ni]);
#pragma unroll
        for (int mi = 0; mi < 4; mi++)
#pragma unroll
            for (int ni = 0; ni < 2; ni++)
                acc[mi][ni] = __builtin_amdgcn_mfma_f32_16x16x32_bf16(
                    av[mi], bv2[ni], acc[mi][ni], 0, 0, 0);
        __syncthreads();
    }
}

// ---------------------------------------------------------------------------
// K2: fused energy (MFMA 8-wave, fp32-equivalent via hi/lo 3-term split).
// grid (128, 2): y=0 -> energy_H at w=blockIdx.x (rows h, stride 16384);
//                y=1 -> energy_W at h=blockIdx.x (rows w, stride 128).
// E = q_hi.k_hi + q_hi.k_lo + q_lo.k_hi  (6 K-steps of 32, slice-selected).
// ---------------------------------------------------------------------------
__global__ __launch_bounds__(512) void energy_mm_kernel(
    const u16* __restrict__ q2, const u16* __restrict__ k2,
    float* __restrict__ attn_f)
{
    __shared__ __align__(16) u16 Asl[128 * 32];
    __shared__ __align__(16) u16 Bsl[128 * 32];
    const int t = threadIdx.x;
    const int lane = t & 63, wid = t >> 6;
    const int wr = wid >> 2, wc = wid & 3;
    const int fr = lane & 15, fq = lane >> 4;
    const int isW = blockIdx.y;              // uniform
    const int fx  = blockIdx.x;

    const size_t sA   = isW ? 128 : (size_t)128 * 128;
    const size_t base = isW ? (size_t)fx * 128 * 128 : (size_t)fx * 128;

    f32x4 acc[4][2];
#pragma unroll
    for (int i = 0; i < 4; i++)
#pragma unroll
        for (int j = 0; j < 2; j++) acc[i][j] = (f32x4){0.f, 0.f, 0.f, 0.f};

    const int srow = wid * 16 + (lane >> 2);
    const int kch  = (lane & 3) ^ ((lane >> 2) & 3);
    const u16* gA = q2 + base + (size_t)srow * sA + kch * 8;
    const u16* gB = k2 + base + (size_t)srow * sA + kch * 8;
    u16* ldsA = Asl + wid * 512;
    u16* ldsB = Bsl + wid * 512;

    FRAG_OFFS_A(aoff)
    FRAG_OFFS_B(boff)

    const int AK[6] = {0, 32, 0, 32, 64, 96};   // q: hi hi hi hi lo lo
    const int BK[6] = {0, 32, 64, 96, 0, 32};   // k: hi hi lo lo hi hi
#pragma unroll
    for (int s = 0; s < 6; s++) {
        gl2lds16(gA + AK[s], ldsA);
        gl2lds16(gB + BK[s], ldsB);
        __syncthreads();
        bf16x8 av[4], bv2[2];
#pragma unroll
        for (int mi = 0; mi < 4; mi++) av[mi] = *(const bf16x8*)(Asl + aoff[mi]);
#pragma unroll
        for (int ni = 0; ni < 2; ni++) bv2[ni] = *(const bf16x8*)(Bsl + boff[ni]);
#pragma unroll
        for (int mi = 0; mi < 4; mi++)
#pragma unroll
            for (int ni = 0; ni < 2; ni++)
                acc[mi][ni] = __builtin_amdgcn_mfma_f32_16x16x32_bf16(
                    av[mi], bv2[ni], acc[mi][ni], 0, 0, 0);
        __syncthreads();
    }

    // epilogue: M index rm (h for eH, w for eW); N index cn (i or j)
#pragma unroll
    for (int ni = 0; ni < 2; ni++) {
        const int cn = wc * 32 + ni * 16 + fr;
#pragma unroll
        for (int mi = 0; mi < 4; mi++) {
            const int rm0 = wr * 64 + mi * 16 + fq * 4;
#pragma unroll
            for (int r = 0; r < 4; r++) {
                const int rm = rm0 + r;
                const size_t prow = isW ? ((size_t)fx * 128 + rm)
                                        : ((size_t)rm * 128 + fx);
                float vv = acc[mi][ni][r];
                if (!isW && cn == rm) vv = NEG_BIG;
                attn_f[prow * 256 + (size_t)isW * 128 + cn] = vv;
            }
        }
    }
}

// ---------------------------------------------------------------------------
// K5: aggA (MFMA 8-wave).  Per (c-tile, w):
//   D[h][c] = sum_i attnH[h,w,i] * v_a[c][w*128+i]
// out_t[(h*128+w)*512 + c] bf16 via LDS re-coalesce (256B rows).
// ---------------------------------------------------------------------------
__global__ __launch_bounds__(512) void aggA_mm_kernel(
    const u16* __restrict__ v_a, const u16* __restrict__ attn_b,
    u16* __restrict__ out_t)
{
    __shared__ __align__(16) u16 Asl[128 * 32];
    __shared__ __align__(16) u16 Bsl[128 * 32];
    __shared__ __align__(16) u16 Dst[128 * 132];
    const int t = threadIdx.x;
    const int lane = t & 63, wid = t >> 6;
    const int wr = wid >> 2, wc = wid & 3;
    const int fr = lane & 15, fq = lane >> 4;
    const int c0 = blockIdx.x * 128;
    const int w  = blockIdx.y;

    f32x4 acc[4][2];
#pragma unroll
    for (int i = 0; i < 4; i++)
#pragma unroll
        for (int j = 0; j < 2; j++) acc[i][j] = (f32x4){0.f, 0.f, 0.f, 0.f};

    FRAG_OFFS_A(aoff)
    FRAG_OFFS_B(boff)

    // A: rows h, stride 128*256 elems; base attn_b + w*256 (H-half of row)
    // B: rows c, stride PP; base v_a + c0*PP + w*128
    mm128_core8(attn_b + (size_t)w * 256, (size_t)128 * 256,
                v_a + (size_t)c0 * PP + (size_t)w * 128, (size_t)PP,
                Asl, Bsl, lane, wid, aoff, boff, acc);

    // stage D[h][c] -> Dst (bf16), then coalesced 256B-row writes
#pragma unroll
    for (int mi = 0; mi < 4; mi++)
#pragma unroll
        for (int ni = 0; ni < 2; ni++) {
            const int c = wc * 32 + ni * 16 + fr;
#pragma unroll
            for (int r = 0; r < 4; r++) {
                const int h = wr * 64 + mi * 16 + fq * 4 + r;
                Dst[h * 132 + c] = f2bf(acc[mi][ni][r]);
            }
        }
    __syncthreads();
#pragma unroll
    for (int s = 0; s < 4; s++) {
        const int h = s * 32 + (t >> 4);
        const int c = (t & 15) * 8;
        ushort4 a0 = *(const ushort4*)(Dst + h * 132 + c);
        ushort4 a1 = *(const ushort4*)(Dst + h * 132 + c + 4);
        ushort4* dp = (ushort4*)(out_t + (size_t)(h * WW + w) * 512 + c0 + c);
        dp[0] = a0; dp[1] = a1;
    }
}

// ---------------------------------------------------------------------------
// K6: aggB (MFMA 8-wave) + fused epilogue.  Per (c-tile, h):
//   D[w][c] = sum_j attnW[h,w,j] * v_c[c][h*128+j]
//   out[c][h][w] = gamma*(D + out_t) + x   (x/out pre-offset per batch)
// ---------------------------------------------------------------------------
template<bool F32>
__device__ __forceinline__ void aggB_mm_body(
    const u16* __restrict__ v_c, const u16* __restrict__ attn_b,
    const u16* __restrict__ out_t, const void* __restrict__ x,
    const void* __restrict__ gamma, void* __restrict__ out,
    u16* Asl, u16* Bsl, char* epi)
{
    const int t = threadIdx.x;
    const int lane = t & 63, wid = t >> 6;
    const int wr = wid >> 2, wc = wid & 3;
    const int fr = lane & 15, fq = lane >> 4;
    const int c0 = blockIdx.x * 128;
    const int h  = blockIdx.y;

    f32x4 acc[4][2];
#pragma unroll
    for (int i = 0; i < 4; i++)
#pragma unroll
        for (int j = 0; j < 2; j++) acc[i][j] = (f32x4){0.f, 0.f, 0.f, 0.f};

    FRAG_OFFS_A(aoff)
    FRAG_OFFS_B(boff)

    // A: rows w, stride 256, base attn_b + h*128*256 + 128 (W-half)
    // B: rows c, stride PP, base v_c + c0*PP + h*128
    mm128_core8(attn_b + (size_t)h * 128 * 256 + 128, (size_t)256,
                v_c + (size_t)c0 * PP + (size_t)h * 128, (size_t)PP,
                Asl, Bsl, lane, wid, aoff, boff, acc);

    // 1) stage out_t tile -> OAs[w][c] (pad 136), coalesced reads
    u16* OAs = (u16*)epi;
#pragma unroll
    for (int s = 0; s < 4; s++) {
        const int wrow = s * 32 + (t >> 4);
        const int c = (t & 15) * 8;
        const u16* sp = out_t + (size_t)(h * WW + wrow) * 512 + c0 + c;
        ushort4 a0 = *(const ushort4*)(sp);
        ushort4 a1 = *(const ushort4*)(sp + 4);
        *(ushort4*)(OAs + wrow * 136 + c)     = a0;
        *(ushort4*)(OAs + wrow * 136 + c + 4) = a1;
    }
    __syncthreads();
    // 2) acc += OA
#pragma unroll
    for (int mi = 0; mi < 4; mi++)
#pragma unroll
        for (int ni = 0; ni < 2; ni++) {
            const int c = wc * 32 + ni * 16 + fr;
#pragma unroll
            for (int r = 0; r < 4; r++) {
                const int ww = wr * 64 + mi * 16 + fq * 4 + r;
                acc[mi][ni][r] += bf2f(OAs[ww * 136 + c]);
            }
        }
    __syncthreads();   // OAs consumed; reuse as DstF

    const float g = ldg<F32>(gamma, 0);
    float* DstF = (float*)epi;       // [64][132] fp32
#pragma unroll
    for (int half = 0; half < 2; half++) {
        if ((wc >> 1) == half) {
#pragma unroll
            for (int mi = 0; mi < 4; mi++)
#pragma unroll
                for (int ni = 0; ni < 2; ni++) {
                    const int cl = (wc & 1) * 32 + ni * 16 + fr;
                    const int w0 = wr * 64 + mi * 16 + fq * 4;
                    f32x4 vv = acc[mi][ni];
                    *(f32x4*)(DstF + cl * 132 + w0) = vv;
                }
        }
        __syncthreads();
#pragma unroll
        for (int s = 0; s < 4; s++) {
            const int e  = s * 2048 + t * 4;
            const int cl = e >> 7;
            const int wq = e & 127;
            f32x4 vv = *(const f32x4*)(DstF + cl * 132 + wq);
            const size_t base = (size_t)(c0 + half * 64 + cl) * PP + h * 128 + wq;
            float r0 = g * vv[0] + ldg<F32>(x, base + 0);
            float r1 = g * vv[1] + ldg<F32>(x, base + 1);
            float r2 = g * vv[2] + ldg<F32>(x, base + 2);
            float r3 = g * vv[3] + ldg<F32>(x, base + 3);
            if (F32) {
                *(float4*)((float*)out + base) = make_float4(r0, r1, r2, r3);
            } else {
                ushort4 o = { f2bf(r0), f2bf(r1), f2bf(r2), f2bf(r3) };
                *(ushort4*)((u16*)out + base) = o;
            }
        }
        __syncthreads();
    }
}

__global__ __launch_bounds__(512) void aggB_mm_kernel(
    const u16* v_c, const u16* attn_b, const u16* out_t,
    const void* x_f32, const void* x_b16, const void* gamma,
    const int* __restrict__ dflag, void* out_f32, void* out_b16)
{
    __shared__ __align__(16) u16 Asl[128 * 32];
    __shared__ __align__(16) u16 Bsl[128 * 32];
    __shared__ __align__(16) char epi[128 * 136 * 2];  // OAs u16[128][136] / DstF f32[64][132]
    if (*dflag)
        aggB_mm_body<true >(v_c, attn_b, out_t, x_f32, gamma, out_f32, Asl, Bsl, epi);
    else
        aggB_mm_body<false>(v_c, attn_b, out_t, x_b16, gamma, out_b16, Asl, Bsl, epi);
}

// ---------------------------------------------------------------------------
// K4: softmax over 256, one wave per row, fp32 -> bf16, finite-guarded.
// ---------------------------------------------------------------------------
__global__ __launch_bounds__(256) void softmax_kernel(
    const float* __restrict__ attn_f, u16* __restrict__ attn_b)
{
    const int wave = threadIdx.x >> 6, lane = threadIdx.x & 63;
    const size_t row = (size_t)blockIdx.x * 4 + wave;
    const float* rp = attn_f + row * 256;
    float4 v = ((const float4*)rp)[lane];
    v.x = isfinite(v.x) ? v.x : NEG_BIG;
    v.y = isfinite(v.y) ? v.y : NEG_BIG;
    v.z = isfinite(v.z) ? v.z : NEG_BIG;
    v.w = isfinite(v.w) ? v.w : NEG_BIG;
    float m = fmaxf(fmaxf(v.x, v.y), fmaxf(v.z, v.w));
#pragma unroll
    for (int off = 32; off; off >>= 1) m = fmaxf(m, __shfl_xor(m, off));
    float e0 = __expf(v.x - m), e1 = __expf(v.y - m);
    float e2 = __expf(v.z - m), e3 = __expf(v.w - m);
    float s = e0 + e1 + e2 + e3;
#pragma unroll
    for (int off = 32; off; off >>= 1) s += __shfl_xor(s, off);
    float inv = 1.0f / s;
    ushort4 u = { f2bf(e0 * inv), f2bf(e1 * inv), f2bf(e2 * inv), f2bf(e3 * inv) };
    ((ushort4*)(attn_b + row * 256))[lane] = u;
}

// ---------------------------------------------------------------------------
extern "C" void kernel_launch(void* const* d_in, const int* in_sizes, int n_in,
                              void* d_out, int out_size, void* d_ws, size_t ws_size,
                              hipStream_t stream)
{
    const void* x     = d_in[0];
    const void* Wq    = d_in[1];
    const void* bq    = d_in[2];
    const void* Wk    = d_in[3];
    const void* bk    = d_in[4];
    const void* Wv    = d_in[5];
    const void* bv    = d_in[6];
    const void* gamma = d_in[7];

    // workspace (~57.3 MiB peak — proven footprint):
    //   dflag | bcat | W_hi/W_lo bf16 | q2 bf16 [p][128] 4MiB | k2 4MiB |
    //   v_c bf16 [c][p] 16MiB | xT_hi 16MiB | xT_lo 16MiB.
    // Overlays (order: trans, projmm, energy, softmax, vtrans, aggA, aggB):
    //   attn_f fp32 16MiB = xT_hi (xT_hi dead after projmm)
    //   v_a    bf16 16MiB = xT_hi (attn_f dead after softmax)
    //   attn_b bf16  8MiB = q2+k2 (dead after energy)
    //   out_t  bf16 16MiB = xT_lo (dead after projmm)
    char* ws = (char*)d_ws;
    int*   dflag = (int*)ws;
    float* bcat  = (float*)(ws + 256);
    size_t off = 4096;
    u16* W_hi = (u16*)(ws + off); off += (size_t)640 * 512 * 2;
    u16* W_lo = (u16*)(ws + off); off += (size_t)640 * 512 * 2;
    u16* q2   = (u16*)(ws + off); off += (size_t)PP * 128 * 2;
    u16* k2   = (u16*)(ws + off); off += (size_t)PP * 128 * 2;
    u16* v_c   = (u16*)(ws + off);  off += (size_t)PP * 512 * 2;
    u16* xT_hi = (u16*)(ws + off);  off += (size_t)PP * 512 * 2;
    u16* xT_lo = (u16*)(ws + off);  off += (size_t)PP * 512 * 2;
    float* attn_f = (float*)xT_hi;
    u16*   v_a    = (u16*)xT_hi;
    u16*   attn_b = (u16*)q2;
    u16*   out_t  = (u16*)xT_lo;

    detect_kernel<<<dim3(1), 256, 0, stream>>>(x, dflag);
    wconv_kernel<<<dim3(640), 256, 0, stream>>>(
        Wq, bq, Wk, bk, Wv, bv, dflag, W_hi, W_lo, bcat);

    for (int b = 0; b < BB; b++) {
        const void* x_f = (const void*)((const float*)x + (size_t)b * CC * PP);
        const void* x_h = (const void*)((const u16*)x   + (size_t)b * CC * PP);
        void* o_f = (void*)((float*)d_out + (size_t)b * CC * PP);
        void* o_h = (void*)((u16*)d_out   + (size_t)b * CC * PP);
        trans_kernel<<<dim3(PP / 64, CC / 64), 256, 0, stream>>>(
            x_f, x_h, dflag, xT_hi, xT_lo);
        projmm_kernel<<<dim3(PP / 128, 5), 512, 0, stream>>>(
            xT_hi, xT_lo, W_hi, W_lo, bcat, q2, k2, v_c);
        energy_mm_kernel<<<dim3(128, 2), 512, 0, stream>>>(q2, k2, attn_f);
        softmax_kernel<<<dim3(PP / 4), 256, 0, stream>>>(attn_f, attn_b);
        vtrans_kernel<<<dim3(CC, 2), 256, 0, stream>>>(v_c, v_a);
        aggA_mm_kernel<<<dim3(4, WW), 512, 0, stream>>>(v_a, attn_b, out_t);
        aggB_mm_kernel<<<dim3(4, HH), 512, 0, stream>>>(
            v_c, attn_b, out_t, x_f, x_h, gamma, dflag, o_f, o_h);
    }
}

// Round 7
// 608.638 us; speedup vs baseline: 2.9575x; 1.0686x over previous
//
#include <hip/hip_runtime.h>
#include <hip/hip_bf16.h>
#include <math.h>

typedef unsigned short u16;

#define BB 4
#define CC 512
#define HH 128
#define WW 128
#define PP (HH*WW)   // 16384 spatial positions per batch

#define NEG_BIG (-3.0e38f)

typedef float f32x4 __attribute__((ext_vector_type(4)));
typedef __bf16 bf16x8 __attribute__((ext_vector_type(8)));

__device__ __forceinline__ float bf2f(u16 u) {
    union { unsigned int i; float f; } v; v.i = ((unsigned int)u) << 16; return v.f;
}
__device__ __forceinline__ u16 f2bf(float f) {
    __hip_bfloat16 h = __float2bfloat16(f);
    u16 u; __builtin_memcpy(&u, &h, 2); return u;
}

template<bool F32>
__device__ __forceinline__ float ldg(const void* p, size_t i) {
    if (F32) return ((const float*)p)[i];
    return bf2f(((const u16*)p)[i]);
}

// async global->LDS, 16B per lane; LDS dest = wave-uniform base + lane*16
__device__ __forceinline__ void gl2lds16(const void* g, void* l) {
    __builtin_amdgcn_global_load_lds(
        (const __attribute__((address_space(1))) unsigned int*)g,
        (__attribute__((address_space(3))) unsigned int*)l,
        16, 0, 0);
}

// ---------------------------------------------------------------------------
// K0: input dtype detection (flag=1 -> fp32).
// ---------------------------------------------------------------------------
__global__ __launch_bounds__(256) void detect_kernel(const void* x, int* flag)
{
    const int t = threadIdx.x;
    const unsigned int* w = (const unsigned int*)x;
    int cnt = 0;
#pragma unroll
    for (int s = 0; s < 16; s++) {
        unsigned int v = w[t * 16 + s];
        int e = (v >> 7) & 0xFF;
        cnt += (e >= 100 && e < 132) ? 1 : 0;
    }
    __shared__ int sh[256];
    sh[t] = cnt;
    __syncthreads();
    for (int o = 128; o; o >>= 1) {
        if (t < o) sh[t] += sh[t + o];
        __syncthreads();
    }
    if (t == 0) *flag = (sh[0] < 2048) ? 1 : 0;
}

// ---------------------------------------------------------------------------
// K0b: weight/bias conversion (once).  [Wq;Wk;Wv] -> [640][512] hi/lo bf16.
// ---------------------------------------------------------------------------
template<bool F32>
__device__ __forceinline__ void wconv_body(
    const void* Wq, const void* bq, const void* Wk, const void* bk,
    const void* Wv, const void* bv,
    u16* __restrict__ Wh, u16* __restrict__ Wl, float* __restrict__ bcat)
{
    const int o = blockIdx.x;
    const int t = threadIdx.x;
#pragma unroll
    for (int s = 0; s < 2; s++) {
        int c = t + s * 256;
        float v;
        if (o < 64)       v = ldg<F32>(Wq, (size_t)o * CC + c);
        else if (o < 128) v = ldg<F32>(Wk, (size_t)(o - 64) * CC + c);
        else              v = ldg<F32>(Wv, (size_t)(o - 128) * CC + c);
        u16 h = f2bf(v);
        Wh[(size_t)o * CC + c] = h;
        Wl[(size_t)o * CC + c] = f2bf(v - bf2f(h));
    }
    if (t == 0) {
        bcat[o] = (o < 64) ? ldg<F32>(bq, o)
                : (o < 128) ? ldg<F32>(bk, o - 64)
                : ldg<F32>(bv, o - 128);
    }
}

__global__ __launch_bounds__(256) void wconv_kernel(
    const void* Wq, const void* bq, const void* Wk, const void* bk,
    const void* Wv, const void* bv, const int* __restrict__ dflag,
    u16* Wh, u16* Wl, float* bcat)
{
    if (*dflag) wconv_body<true >(Wq, bq, Wk, bk, Wv, bv, Wh, Wl, bcat);
    else        wconv_body<false>(Wq, bq, Wk, bk, Wv, bv, Wh, Wl, bcat);
}

// ---------------------------------------------------------------------------
// K0c: per-batch transpose+split: x [512][16384] -> xT_hi/xT_lo [16384][512] bf16.
// ---------------------------------------------------------------------------
template<bool F32>
__device__ __forceinline__ void trans_body(
    const void* __restrict__ x, u16* __restrict__ xh, u16* __restrict__ xl,
    float (*T)[65])
{
    const int t = threadIdx.x;
    const int p0 = blockIdx.x * 64;
    const int c0 = blockIdx.y * 64;
    {
        const int pp = t & 63;
        const int cb = t >> 6;   // 0..3
#pragma unroll
        for (int s = 0; s < 16; s++) {
            int cc = cb * 16 + s;
            T[cc][pp] = ldg<F32>(x, (size_t)(c0 + cc) * PP + p0 + pp);
        }
    }
    __syncthreads();
    {
        const int pr = t >> 2;          // 0..63
        const int cb = (t & 3) * 16;    // 0,16,32,48
        u16 hi[16], lo[16];
#pragma unroll
        for (int j = 0; j < 16; j++) {
            float v = T[cb + j][pr];
            u16 h = f2bf(v);
            hi[j] = h;
            lo[j] = f2bf(v - bf2f(h));
        }
        size_t base = (size_t)(p0 + pr) * 512 + c0 + cb;
#pragma unroll
        for (int s = 0; s < 4; s++) {
            *(ushort4*)(xh + base + s * 4) = *(ushort4*)(hi + s * 4);
            *(ushort4*)(xl + base + s * 4) = *(ushort4*)(lo + s * 4);
        }
    }
}

__global__ __launch_bounds__(256) void trans_kernel(
    const void* x_f32, const void* x_b16, const int* __restrict__ dflag,
    u16* xh, u16* xl)
{
    __shared__ float T[64][65];
    if (*dflag) trans_body<true >(x_f32, xh, xl, T);
    else        trans_body<false>(x_b16, xh, xl, T);
}

// ---------------------------------------------------------------------------
// 8-wave BK=64 MFMA family: 512 threads = 2x4 waves; wave (wr,wc) owns a
// 64x32 sub-tile; acc[4][2] of f32x4.  LDS tiles [128 rows][64 k] bf16 with
// full 8-slot XOR swizzle: LDS slot c holds global k-chunk (c ^ (row&7)).
// Each wave stages 16 rows x 64 k per operand = 2 gl2lds16 calls (rows s*8..);
// row&7 is equal for s=0/s=1 (delta 8) so the per-lane source chunk is shared.
// 16 MFMA per barrier pair (2 k-halves of 32).
// ---------------------------------------------------------------------------
#define FRAG_OFFS_A64(arr)                                          \
    int arr[4][2];                                                  \
    _Pragma("unroll")                                               \
    for (int ii = 0; ii < 4; ii++) {                                \
        int row = wr * 64 + ii * 16 + fr;                           \
        _Pragma("unroll")                                           \
        for (int hf = 0; hf < 2; hf++)                              \
            arr[ii][hf] = row * 64 + (((hf * 4 + fq) ^ (row & 7)) * 8); \
    }
#define FRAG_OFFS_B64(arr)                                          \
    int arr[2][2];                                                  \
    _Pragma("unroll")                                               \
    for (int ii = 0; ii < 2; ii++) {                                \
        int row = wc * 32 + ii * 16 + fr;                           \
        _Pragma("unroll")                                           \
        for (int hf = 0; hf < 2; hf++)                              \
            arr[ii][hf] = row * 64 + (((hf * 4 + fq) ^ (row & 7)) * 8); \
    }

// ---------------------------------------------------------------------------
// K1: MFMA split-GEMM projection (8-wave, BK=64).
// Tile 0 (o0=0, q/k): K'=1536 (x_hi.W_hi | x_hi.W_lo | x_lo.W_hi) ~ fp32.
// Tiles 1..4 (V): K'=512, single x_hi.W_hi term (bf16 v storage dominates).
// q -> q2 bf16 [p][128] = [q_hi|q_lo]; k -> k2 likewise; v -> v_c bf16 [c][p].
// ---------------------------------------------------------------------------
__global__ __launch_bounds__(512) void projmm_kernel(
    const u16* __restrict__ xT_hi, const u16* __restrict__ xT_lo,
    const u16* __restrict__ W_hi,  const u16* __restrict__ W_lo,
    const float* __restrict__ bcat,
    u16* __restrict__ q2, u16* __restrict__ k2, u16* __restrict__ v_c)
{
    __shared__ __align__(16) u16 Asl[128 * 64];
    __shared__ __align__(16) u16 Bsl[128 * 64];
    const int t = threadIdx.x;
    const int lane = t & 63, wid = t >> 6;      // wid 0..7
    const int wr = wid >> 2, wc = wid & 3;
    const int fr = lane & 15, fq = lane >> 4;
    const int p0 = blockIdx.x * 128;
    const int o0 = blockIdx.y * 128;
    const int KTOT = (blockIdx.y == 0) ? 1536 : 512;

    f32x4 acc[4][2];
#pragma unroll
    for (int i = 0; i < 4; i++)
#pragma unroll
        for (int j = 0; j < 2; j++) acc[i][j] = (f32x4){0.f, 0.f, 0.f, 0.f};

    const int srow_l = lane >> 3;               // 0..7
    const int gk     = ((lane & 7) ^ srow_l) * 8;
    const int row0   = wid * 16 + srow_l;       // 0..127
    const size_t gA0 = (size_t)(p0 + row0) * 512 + gk;
    const size_t gB0 = (size_t)(o0 + row0) * 512 + gk;
    u16* ldsA = Asl + wid * 1024;
    u16* ldsB = Bsl + wid * 1024;

    FRAG_OFFS_A64(aoff)
    FRAG_OFFS_B64(boff)

    for (int k0 = 0; k0 < KTOT; k0 += 64) {
        const int rg = k0 >> 9;          // 0,1,2 (uniform)
        const int kc = k0 & 511;
        const u16* xs   = (rg == 2) ? xT_lo : xT_hi;
        const u16* wsrc = (rg == 1) ? W_lo  : W_hi;
        gl2lds16(xs + gA0 + kc,            ldsA);
        gl2lds16(xs + gA0 + 8 * 512 + kc,  ldsA + 512);
        gl2lds16(wsrc + gB0 + kc,           ldsB);
        gl2lds16(wsrc + gB0 + 8 * 512 + kc, ldsB + 512);
        __syncthreads();

#pragma unroll
        for (int hf = 0; hf < 2; hf++) {
            bf16x8 av[4], bv2[2];
#pragma unroll
            for (int mi = 0; mi < 4; mi++) av[mi] = *(const bf16x8*)(Asl + aoff[mi][hf]);
#pragma unroll
            for (int ni = 0; ni < 2; ni++) bv2[ni] = *(const bf16x8*)(Bsl + boff[ni][hf]);
#pragma unroll
            for (int mi = 0; mi < 4; mi++)
#pragma unroll
                for (int ni = 0; ni < 2; ni++)
                    acc[mi][ni] = __builtin_amdgcn_mfma_f32_16x16x32_bf16(
                        av[mi], bv2[ni], acc[mi][ni], 0, 0, 0);
        }
        __syncthreads();
    }

    // epilogue: row p = p0+wr*64+mi*16+fq*4+r, col o = o0+wc*32+ni*16+fr
#pragma unroll
    for (int ni = 0; ni < 2; ni++) {
        const int o = o0 + wc * 32 + ni * 16 + fr;
        const float bb = bcat[o];
        if (o < 64) {
#pragma unroll
            for (int mi = 0; mi < 4; mi++) {
                const int pb = p0 + wr * 64 + mi * 16 + fq * 4;
#pragma unroll
                for (int r = 0; r < 4; r++) {
                    float val = acc[mi][ni][r] + bb;
                    u16 hi = f2bf(val);
                    q2[(size_t)(pb + r) * 128 + o]      = hi;
                    q2[(size_t)(pb + r) * 128 + 64 + o] = f2bf(val - bf2f(hi));
                }
            }
        } else if (o < 128) {
            const int oc = o - 64;
#pragma unroll
            for (int mi = 0; mi < 4; mi++) {
                const int pb = p0 + wr * 64 + mi * 16 + fq * 4;
#pragma unroll
                for (int r = 0; r < 4; r++) {
                    float val = acc[mi][ni][r] + bb;
                    u16 hi = f2bf(val);
                    k2[(size_t)(pb + r) * 128 + oc]      = hi;
                    k2[(size_t)(pb + r) * 128 + 64 + oc] = f2bf(val - bf2f(hi));
                }
            }
        } else {
            const int ch = o - 128;
#pragma unroll
            for (int mi = 0; mi < 4; mi++) {
                const int pb = p0 + wr * 64 + mi * 16 + fq * 4;
                ushort4 u = { f2bf(acc[mi][ni][0] + bb), f2bf(acc[mi][ni][1] + bb),
                              f2bf(acc[mi][ni][2] + bb), f2bf(acc[mi][ni][3] + bb) };
                *(ushort4*)(v_c + (size_t)ch * PP + pb) = u;
            }
        }
    }
}

// ---------------------------------------------------------------------------
// K1b: v spatial transpose: v_a[c][w*128+h] = v_c[c][h*128+w].
// Runs AFTER softmax so v_a can overlay the dead attn_f region.
// ---------------------------------------------------------------------------
__global__ __launch_bounds__(256) void vtrans_kernel(
    const u16* __restrict__ v_c, u16* __restrict__ v_a)
{
    const int c  = blockIdx.x;
    const int w0 = blockIdx.y * 64;
    const int t  = threadIdx.x;
    __shared__ __align__(16) u16 T[64 * 132];   // [wl][h], pad 132
#pragma unroll
    for (int s = 0; s < 4; s++) {
        const int h  = (t >> 3) + s * 32;
        const int wl = (t & 7) * 8;
        const u16* src = v_c + (size_t)c * PP + h * 128 + w0 + wl;
        ushort4 a0 = *(const ushort4*)(src);
        ushort4 a1 = *(const ushort4*)(src + 4);
        T[(wl + 0) * 132 + h] = a0.x; T[(wl + 1) * 132 + h] = a0.y;
        T[(wl + 2) * 132 + h] = a0.z; T[(wl + 3) * 132 + h] = a0.w;
        T[(wl + 4) * 132 + h] = a1.x; T[(wl + 5) * 132 + h] = a1.y;
        T[(wl + 6) * 132 + h] = a1.z; T[(wl + 7) * 132 + h] = a1.w;
    }
    __syncthreads();
#pragma unroll
    for (int s = 0; s < 4; s++) {
        const int wl = (t >> 4) + s * 16;
        const int hh = (t & 15) * 8;
        ushort4 b0 = *(const ushort4*)(T + wl * 132 + hh);
        ushort4 b1 = *(const ushort4*)(T + wl * 132 + hh + 4);
        ushort4* dp = (ushort4*)(v_a + (size_t)c * PP + (size_t)(w0 + wl) * 128 + hh);
        dp[0] = b0; dp[1] = b1;
    }
}

// ---------------------------------------------------------------------------
// shared 128x128(K=128) bf16 MFMA core, 8-wave BK=64 variant (2 K-steps).
// ---------------------------------------------------------------------------
__device__ __forceinline__ void mm128_core8(
    const u16* __restrict__ baseA, size_t sA,
    const u16* __restrict__ baseB, size_t sB,
    u16* Asl, u16* Bsl, int lane, int wid,
    const int (*aoff)[2], const int (*boff)[2], f32x4 (*acc)[2])
{
    const int srow_l = lane >> 3;
    const int gk     = ((lane & 7) ^ srow_l) * 8;
    const int row0   = wid * 16 + srow_l;
    const u16* gA = baseA + (size_t)row0 * sA + gk;
    const u16* gB = baseB + (size_t)row0 * sB + gk;
    u16* ldsA = Asl + wid * 1024;
    u16* ldsB = Bsl + wid * 1024;
    for (int k0 = 0; k0 < 128; k0 += 64) {
        gl2lds16(gA + k0,           ldsA);
        gl2lds16(gA + 8 * sA + k0,  ldsA + 512);
        gl2lds16(gB + k0,           ldsB);
        gl2lds16(gB + 8 * sB + k0,  ldsB + 512);
        __syncthreads();
#pragma unroll
        for (int hf = 0; hf < 2; hf++) {
            bf16x8 av[4], bv2[2];
#pragma unroll
            for (int mi = 0; mi < 4; mi++) av[mi] = *(const bf16x8*)(Asl + aoff[mi][hf]);
#pragma unroll
            for (int ni = 0; ni < 2; ni++) bv2[ni] = *(const bf16x8*)(Bsl + boff[ni][hf]);
#pragma unroll
            for (int mi = 0; mi < 4; mi++)
#pragma unroll
                for (int ni = 0; ni < 2; ni++)
                    acc[mi][ni] = __builtin_amdgcn_mfma_f32_16x16x32_bf16(
                        av[mi], bv2[ni], acc[mi][ni], 0, 0, 0);
        }
        __syncthreads();
    }
}

// ---------------------------------------------------------------------------
// K2: fused energy (MFMA 8-wave BK=64, fp32-equivalent via hi/lo 3 terms).
// grid (128, 2): y=0 -> energy_H at w=blockIdx.x (rows h, stride 16384);
//                y=1 -> energy_W at h=blockIdx.x (rows w, stride 128).
// E = q_hi.k_hi + q_hi.k_lo + q_lo.k_hi  (3 K-steps of 64, slice-selected).
// ---------------------------------------------------------------------------
__global__ __launch_bounds__(512) void energy_mm_kernel(
    const u16* __restrict__ q2, const u16* __restrict__ k2,
    float* __restrict__ attn_f)
{
    __shared__ __align__(16) u16 Asl[128 * 64];
    __shared__ __align__(16) u16 Bsl[128 * 64];
    const int t = threadIdx.x;
    const int lane = t & 63, wid = t >> 6;
    const int wr = wid >> 2, wc = wid & 3;
    const int fr = lane & 15, fq = lane >> 4;
    const int isW = blockIdx.y;              // uniform
    const int fx  = blockIdx.x;

    const size_t sA   = isW ? 128 : (size_t)128 * 128;
    const size_t base = isW ? (size_t)fx * 128 * 128 : (size_t)fx * 128;

    f32x4 acc[4][2];
#pragma unroll
    for (int i = 0; i < 4; i++)
#pragma unroll
        for (int j = 0; j < 2; j++) acc[i][j] = (f32x4){0.f, 0.f, 0.f, 0.f};

    const int srow_l = lane >> 3;
    const int gk     = ((lane & 7) ^ srow_l) * 8;
    const int row0   = wid * 16 + srow_l;
    const u16* gA = q2 + base + (size_t)row0 * sA + gk;
    const u16* gB = k2 + base + (size_t)row0 * sA + gk;
    u16* ldsA = Asl + wid * 1024;
    u16* ldsB = Bsl + wid * 1024;

    FRAG_OFFS_A64(aoff)
    FRAG_OFFS_B64(boff)

    const int AO[3] = {0, 0, 64};    // q: hi hi lo
    const int BO[3] = {0, 64, 0};    // k: hi lo hi
#pragma unroll
    for (int s = 0; s < 3; s++) {
        gl2lds16(gA + AO[s],           ldsA);
        gl2lds16(gA + 8 * sA + AO[s],  ldsA + 512);
        gl2lds16(gB + BO[s],           ldsB);
        gl2lds16(gB + 8 * sA + BO[s],  ldsB + 512);
        __syncthreads();
#pragma unroll
        for (int hf = 0; hf < 2; hf++) {
            bf16x8 av[4], bv2[2];
#pragma unroll
            for (int mi = 0; mi < 4; mi++) av[mi] = *(const bf16x8*)(Asl + aoff[mi][hf]);
#pragma unroll
            for (int ni = 0; ni < 2; ni++) bv2[ni] = *(const bf16x8*)(Bsl + boff[ni][hf]);
#pragma unroll
            for (int mi = 0; mi < 4; mi++)
#pragma unroll
                for (int ni = 0; ni < 2; ni++)
                    acc[mi][ni] = __builtin_amdgcn_mfma_f32_16x16x32_bf16(
                        av[mi], bv2[ni], acc[mi][ni], 0, 0, 0);
        }
        __syncthreads();
    }

    // epilogue: M index rm (h for eH, w for eW); N index cn (i or j)
#pragma unroll
    for (int ni = 0; ni < 2; ni++) {
        const int cn = wc * 32 + ni * 16 + fr;
#pragma unroll
        for (int mi = 0; mi < 4; mi++) {
            const int rm0 = wr * 64 + mi * 16 + fq * 4;
#pragma unroll
            for (int r = 0; r < 4; r++) {
                const int rm = rm0 + r;
                const size_t prow = isW ? ((size_t)fx * 128 + rm)
                                        : ((size_t)rm * 128 + fx);
                float vv = acc[mi][ni][r];
                if (!isW && cn == rm) vv = NEG_BIG;
                attn_f[prow * 256 + (size_t)isW * 128 + cn] = vv;
            }
        }
    }
}

// ---------------------------------------------------------------------------
// K5: aggA (MFMA 8-wave BK=64).  Per (c-tile, w):
//   D[h][c] = sum_i attnH[h,w,i] * v_a[c][w*128+i]
// out_t[(h*128+w)*512 + c] bf16 via LDS re-coalesce.  Dst aliases Asl/Bsl
// (dead after the K-loop) -> static LDS 33 KB.
// ---------------------------------------------------------------------------
__global__ __launch_bounds__(512) void aggA_mm_kernel(
    const u16* __restrict__ v_a, const u16* __restrict__ attn_b,
    u16* __restrict__ out_t)
{
    __shared__ __align__(16) char smem[128 * 132 * 2];  // >= 2x16KB gemm tiles
    u16* Asl = (u16*)smem;
    u16* Bsl = (u16*)(smem + 128 * 64 * 2);
    u16* Dst = (u16*)smem;                               // [128][132] after loop
    const int t = threadIdx.x;
    const int lane = t & 63, wid = t >> 6;
    const int wr = wid >> 2, wc = wid & 3;
    const int fr = lane & 15, fq = lane >> 4;
    const int c0 = blockIdx.x * 128;
    const int w  = blockIdx.y;

    f32x4 acc[4][2];
#pragma unroll
    for (int i = 0; i < 4; i++)
#pragma unroll
        for (int j = 0; j < 2; j++) acc[i][j] = (f32x4){0.f, 0.f, 0.f, 0.f};

    FRAG_OFFS_A64(aoff)
    FRAG_OFFS_B64(boff)

    // A: rows h, stride 128*256 elems; base attn_b + w*256 (H-half of row)
    // B: rows c, stride PP; base v_a + c0*PP + w*128
    mm128_core8(attn_b + (size_t)w * 256, (size_t)128 * 256,
                v_a + (size_t)c0 * PP + (size_t)w * 128, (size_t)PP,
                Asl, Bsl, lane, wid, aoff, boff, acc);

    // stage D[h][c] -> Dst (bf16), then coalesced 256B-row writes
#pragma unroll
    for (int mi = 0; mi < 4; mi++)
#pragma unroll
        for (int ni = 0; ni < 2; ni++) {
            const int c = wc * 32 + ni * 16 + fr;
#pragma unroll
            for (int r = 0; r < 4; r++) {
                const int h = wr * 64 + mi * 16 + fq * 4 + r;
                Dst[h * 132 + c] = f2bf(acc[mi][ni][r]);
            }
        }
    __syncthreads();
#pragma unroll
    for (int s = 0; s < 4; s++) {
        const int h = s * 32 + (t >> 4);
        const int c = (t & 15) * 8;
        ushort4 a0 = *(const ushort4*)(Dst + h * 132 + c);
        ushort4 a1 = *(const ushort4*)(Dst + h * 132 + c + 4);
        ushort4* dp = (ushort4*)(out_t + (size_t)(h * WW + w) * 512 + c0 + c);
        dp[0] = a0; dp[1] = a1;
    }
}

// ---------------------------------------------------------------------------
// K6: aggB (MFMA 8-wave BK=64) + fused epilogue.  Per (c-tile, h):
//   D[w][c] = sum_j attnW[h,w,j] * v_c[c][h*128+j]
//   out[c][h][w] = gamma*(D + out_t) + x   (x/out pre-offset per batch)
// epi aliases Asl/Bsl (dead after the K-loop) -> static LDS 34 KB.
// ---------------------------------------------------------------------------
template<bool F32>
__device__ __forceinline__ void aggB_mm_body(
    const u16* __restrict__ v_c, const u16* __restrict__ attn_b,
    const u16* __restrict__ out_t, const void* __restrict__ x,
    const void* __restrict__ gamma, void* __restrict__ out,
    char* smem)
{
    u16* Asl = (u16*)smem;
    u16* Bsl = (u16*)(smem + 128 * 64 * 2);
    char* epi = smem;
    const int t = threadIdx.x;
    const int lane = t & 63, wid = t >> 6;
    const int wr = wid >> 2, wc = wid & 3;
    const int fr = lane & 15, fq = lane >> 4;
    const int c0 = blockIdx.x * 128;
    const int h  = blockIdx.y;

    f32x4 acc[4][2];
#pragma unroll
    for (int i = 0; i < 4; i++)
#pragma unroll
        for (int j = 0; j < 2; j++) acc[i][j] = (f32x4){0.f, 0.f, 0.f, 0.f};

    FRAG_OFFS_A64(aoff)
    FRAG_OFFS_B64(boff)

    // A: rows w, stride 256, base attn_b + h*128*256 + 128 (W-half)
    // B: rows c, stride PP, base v_c + c0*PP + h*128
    mm128_core8(attn_b + (size_t)h * 128 * 256 + 128, (size_t)256,
                v_c + (size_t)c0 * PP + (size_t)h * 128, (size_t)PP,
                Asl, Bsl, lane, wid, aoff, boff, acc);

    // 1) stage out_t tile -> OAs[w][c] (pad 136), coalesced reads
    u16* OAs = (u16*)epi;
#pragma unroll
    for (int s = 0; s < 4; s++) {
        const int wrow = s * 32 + (t >> 4);
        const int c = (t & 15) * 8;
        const u16* sp = out_t + (size_t)(h * WW + wrow) * 512 + c0 + c;
        ushort4 a0 = *(const ushort4*)(sp);
        ushort4 a1 = *(const ushort4*)(sp + 4);
        *(ushort4*)(OAs + wrow * 136 + c)     = a0;
        *(ushort4*)(OAs + wrow * 136 + c + 4) = a1;
    }
    __syncthreads();
    // 2) acc += OA
#pragma unroll
    for (int mi = 0; mi < 4; mi++)
#pragma unroll
        for (int ni = 0; ni < 2; ni++) {
            const int c = wc * 32 + ni * 16 + fr;
#pragma unroll
            for (int r = 0; r < 4; r++) {
                const int ww = wr * 64 + mi * 16 + fq * 4 + r;
                acc[mi][ni][r] += bf2f(OAs[ww * 136 + c]);
            }
        }
    __syncthreads();   // OAs consumed; reuse as DstF

    const float g = ldg<F32>(gamma, 0);
    float* DstF = (float*)epi;       // [64][132] fp32
#pragma unroll
    for (int half = 0; half < 2; half++) {
        if ((wc >> 1) == half) {
#pragma unroll
            for (int mi = 0; mi < 4; mi++)
#pragma unroll
                for (int ni = 0; ni < 2; ni++) {
                    const int cl = (wc & 1) * 32 + ni * 16 + fr;
                    const int w0 = wr * 64 + mi * 16 + fq * 4;
                    f32x4 vv = acc[mi][ni];
                    *(f32x4*)(DstF + cl * 132 + w0) = vv;
                }
        }
        __syncthreads();
#pragma unroll
        for (int s = 0; s < 4; s++) {
            const int e  = s * 2048 + t * 4;
            const int cl = e >> 7;
            const int wq = e & 127;
            f32x4 vv = *(const f32x4*)(DstF + cl * 132 + wq);
            const size_t base = (size_t)(c0 + half * 64 + cl) * PP + h * 128 + wq;
            float r0 = g * vv[0] + ldg<F32>(x, base + 0);
            float r1 = g * vv[1] + ldg<F32>(x, base + 1);
            float r2 = g * vv[2] + ldg<F32>(x, base + 2);
            float r3 = g * vv[3] + ldg<F32>(x, base + 3);
            if (F32) {
                *(float4*)((float*)out + base) = make_float4(r0, r1, r2, r3);
            } else {
                ushort4 o = { f2bf(r0), f2bf(r1), f2bf(r2), f2bf(r3) };
                *(ushort4*)((u16*)out + base) = o;
            }
        }
        __syncthreads();
    }
}

__global__ __launch_bounds__(512) void aggB_mm_kernel(
    const u16* v_c, const u16* attn_b, const u16* out_t,
    const void* x_f32, const void* x_b16, const void* gamma,
    const int* __restrict__ dflag, void* out_f32, void* out_b16)
{
    __shared__ __align__(16) char smem[128 * 136 * 2];  // >= 2x16KB gemm tiles
    if (*dflag)
        aggB_mm_body<true >(v_c, attn_b, out_t, x_f32, gamma, out_f32, smem);
    else
        aggB_mm_body<false>(v_c, attn_b, out_t, x_b16, gamma, out_b16, smem);
}

// ---------------------------------------------------------------------------
// K4: softmax over 256, one wave per row, fp32 -> bf16, finite-guarded.
// ---------------------------------------------------------------------------
__global__ __launch_bounds__(256) void softmax_kernel(
    const float* __restrict__ attn_f, u16* __restrict__ attn_b)
{
    const int wave = threadIdx.x >> 6, lane = threadIdx.x & 63;
    const size_t row = (size_t)blockIdx.x * 4 + wave;
    const float* rp = attn_f + row * 256;
    float4 v = ((const float4*)rp)[lane];
    v.x = isfinite(v.x) ? v.x : NEG_BIG;
    v.y = isfinite(v.y) ? v.y : NEG_BIG;
    v.z = isfinite(v.z) ? v.z : NEG_BIG;
    v.w = isfinite(v.w) ? v.w : NEG_BIG;
    float m = fmaxf(fmaxf(v.x, v.y), fmaxf(v.z, v.w));
#pragma unroll
    for (int off = 32; off; off >>= 1) m = fmaxf(m, __shfl_xor(m, off));
    float e0 = __expf(v.x - m), e1 = __expf(v.y - m);
    float e2 = __expf(v.z - m), e3 = __expf(v.w - m);
    float s = e0 + e1 + e2 + e3;
#pragma unroll
    for (int off = 32; off; off >>= 1) s += __shfl_xor(s, off);
    float inv = 1.0f / s;
    ushort4 u = { f2bf(e0 * inv), f2bf(e1 * inv), f2bf(e2 * inv), f2bf(e3 * inv) };
    ((ushort4*)(attn_b + row * 256))[lane] = u;
}

// ---------------------------------------------------------------------------
extern "C" void kernel_launch(void* const* d_in, const int* in_sizes, int n_in,
                              void* d_out, int out_size, void* d_ws, size_t ws_size,
                              hipStream_t stream)
{
    const void* x     = d_in[0];
    const void* Wq    = d_in[1];
    const void* bq    = d_in[2];
    const void* Wk    = d_in[3];
    const void* bk    = d_in[4];
    const void* Wv    = d_in[5];
    const void* bv    = d_in[6];
    const void* gamma = d_in[7];

    // workspace (~57.3 MiB peak — proven footprint):
    //   dflag | bcat | W_hi/W_lo bf16 | q2 bf16 [p][128] 4MiB | k2 4MiB |
    //   v_c bf16 [c][p] 16MiB | xT_hi 16MiB | xT_lo 16MiB.
    // Overlays (order: trans, projmm, energy, softmax, vtrans, aggA, aggB):
    //   attn_f fp32 16MiB = xT_hi (xT_hi dead after projmm)
    //   v_a    bf16 16MiB = xT_hi (attn_f dead after softmax)
    //   attn_b bf16  8MiB = q2+k2 (dead after energy)
    //   out_t  bf16 16MiB = xT_lo (dead after projmm)
    char* ws = (char*)d_ws;
    int*   dflag = (int*)ws;
    float* bcat  = (float*)(ws + 256);
    size_t off = 4096;
    u16* W_hi = (u16*)(ws + off); off += (size_t)640 * 512 * 2;
    u16* W_lo = (u16*)(ws + off); off += (size_t)640 * 512 * 2;
    u16* q2   = (u16*)(ws + off); off += (size_t)PP * 128 * 2;
    u16* k2   = (u16*)(ws + off); off += (size_t)PP * 128 * 2;
    u16* v_c   = (u16*)(ws + off);  off += (size_t)PP * 512 * 2;
    u16* xT_hi = (u16*)(ws + off);  off += (size_t)PP * 512 * 2;
    u16* xT_lo = (u16*)(ws + off);  off += (size_t)PP * 512 * 2;
    float* attn_f = (float*)xT_hi;
    u16*   v_a    = (u16*)xT_hi;
    u16*   attn_b = (u16*)q2;
    u16*   out_t  = (u16*)xT_lo;

    detect_kernel<<<dim3(1), 256, 0, stream>>>(x, dflag);
    wconv_kernel<<<dim3(640), 256, 0, stream>>>(
        Wq, bq, Wk, bk, Wv, bv, dflag, W_hi, W_lo, bcat);

    for (int b = 0; b < BB; b++) {
        const void* x_f = (const void*)((const float*)x + (size_t)b * CC * PP);
        const void* x_h = (const void*)((const u16*)x   + (size_t)b * CC * PP);
        void* o_f = (void*)((float*)d_out + (size_t)b * CC * PP);
        void* o_h = (void*)((u16*)d_out   + (size_t)b * CC * PP);
        trans_kernel<<<dim3(PP / 64, CC / 64), 256, 0, stream>>>(
            x_f, x_h, dflag, xT_hi, xT_lo);
        projmm_kernel<<<dim3(PP / 128, 5), 512, 0, stream>>>(
            xT_hi, xT_lo, W_hi, W_lo, bcat, q2, k2, v_c);
        energy_mm_kernel<<<dim3(128, 2), 512, 0, stream>>>(q2, k2, attn_f);
        softmax_kernel<<<dim3(PP / 4), 256, 0, stream>>>(attn_f, attn_b);
        vtrans_kernel<<<dim3(CC, 2), 256, 0, stream>>>(v_c, v_a);
        aggA_mm_kernel<<<dim3(4, WW), 512, 0, stream>>>(v_a, attn_b, out_t);
        aggB_mm_kernel<<<dim3(4, HH), 512, 0, stream>>>(
            v_c, attn_b, out_t, x_f, x_h, gamma, dflag, o_f, o_h);
    }
}

// Round 8
// 563.143 us; speedup vs baseline: 3.1965x; 1.0808x over previous
//
#include <hip/hip_runtime.h>
#include <hip/hip_bf16.h>
#include <math.h>

typedef unsigned short u16;

#define BB 4
#define CC 512
#define HH 128
#define WW 128
#define PP (HH*WW)   // 16384 spatial positions per batch

#define NEG_BIG (-3.0e38f)

typedef float f32x4 __attribute__((ext_vector_type(4)));
typedef __bf16 bf16x8 __attribute__((ext_vector_type(8)));

__device__ __forceinline__ float bf2f(u16 u) {
    union { unsigned int i; float f; } v; v.i = ((unsigned int)u) << 16; return v.f;
}
__device__ __forceinline__ u16 f2bf(float f) {
    __hip_bfloat16 h = __float2bfloat16(f);
    u16 u; __builtin_memcpy(&u, &h, 2); return u;
}

template<bool F32>
__device__ __forceinline__ float ldg(const void* p, size_t i) {
    if (F32) return ((const float*)p)[i];
    return bf2f(((const u16*)p)[i]);
}

// async global->LDS, 16B per lane; LDS dest = wave-uniform base + lane*16
__device__ __forceinline__ void gl2lds16(const void* g, void* l) {
    __builtin_amdgcn_global_load_lds(
        (const __attribute__((address_space(1))) unsigned int*)g,
        (__attribute__((address_space(3))) unsigned int*)l,
        16, 0, 0);
}

// ---------------------------------------------------------------------------
// K0: input dtype detection (flag=1 -> fp32).
// ---------------------------------------------------------------------------
__global__ __launch_bounds__(256) void detect_kernel(const void* x, int* flag)
{
    const int t = threadIdx.x;
    const unsigned int* w = (const unsigned int*)x;
    int cnt = 0;
#pragma unroll
    for (int s = 0; s < 16; s++) {
        unsigned int v = w[t * 16 + s];
        int e = (v >> 7) & 0xFF;
        cnt += (e >= 100 && e < 132) ? 1 : 0;
    }
    __shared__ int sh[256];
    sh[t] = cnt;
    __syncthreads();
    for (int o = 128; o; o >>= 1) {
        if (t < o) sh[t] += sh[t + o];
        __syncthreads();
    }
    if (t == 0) *flag = (sh[0] < 2048) ? 1 : 0;
}

// ---------------------------------------------------------------------------
// K0b: weight/bias conversion (once).  [Wq;Wk;Wv] -> [640][512] hi/lo bf16.
// ---------------------------------------------------------------------------
template<bool F32>
__device__ __forceinline__ void wconv_body(
    const void* Wq, const void* bq, const void* Wk, const void* bk,
    const void* Wv, const void* bv,
    u16* __restrict__ Wh, u16* __restrict__ Wl, float* __restrict__ bcat)
{
    const int o = blockIdx.x;
    const int t = threadIdx.x;
#pragma unroll
    for (int s = 0; s < 2; s++) {
        int c = t + s * 256;
        float v;
        if (o < 64)       v = ldg<F32>(Wq, (size_t)o * CC + c);
        else if (o < 128) v = ldg<F32>(Wk, (size_t)(o - 64) * CC + c);
        else              v = ldg<F32>(Wv, (size_t)(o - 128) * CC + c);
        u16 h = f2bf(v);
        Wh[(size_t)o * CC + c] = h;
        Wl[(size_t)o * CC + c] = f2bf(v - bf2f(h));
    }
    if (t == 0) {
        bcat[o] = (o < 64) ? ldg<F32>(bq, o)
                : (o < 128) ? ldg<F32>(bk, o - 64)
                : ldg<F32>(bv, o - 128);
    }
}

__global__ __launch_bounds__(256) void wconv_kernel(
    const void* Wq, const void* bq, const void* Wk, const void* bk,
    const void* Wv, const void* bv, const int* __restrict__ dflag,
    u16* Wh, u16* Wl, float* bcat)
{
    if (*dflag) wconv_body<true >(Wq, bq, Wk, bk, Wv, bv, Wh, Wl, bcat);
    else        wconv_body<false>(Wq, bq, Wk, bk, Wv, bv, Wh, Wl, bcat);
}

// ---------------------------------------------------------------------------
// K0c: per-batch transpose+split: x [512][16384] -> xT_hi/xT_lo [16384][512] bf16.
// ---------------------------------------------------------------------------
template<bool F32>
__device__ __forceinline__ void trans_body(
    const void* __restrict__ x, u16* __restrict__ xh, u16* __restrict__ xl,
    float (*T)[65])
{
    const int t = threadIdx.x;
    const int p0 = blockIdx.x * 64;
    const int c0 = blockIdx.y * 64;
    {
        const int pp = t & 63;
        const int cb = t >> 6;   // 0..3
#pragma unroll
        for (int s = 0; s < 16; s++) {
            int cc = cb * 16 + s;
            T[cc][pp] = ldg<F32>(x, (size_t)(c0 + cc) * PP + p0 + pp);
        }
    }
    __syncthreads();
    {
        const int pr = t >> 2;          // 0..63
        const int cb = (t & 3) * 16;    // 0,16,32,48
        u16 hi[16], lo[16];
#pragma unroll
        for (int j = 0; j < 16; j++) {
            float v = T[cb + j][pr];
            u16 h = f2bf(v);
            hi[j] = h;
            lo[j] = f2bf(v - bf2f(h));
        }
        size_t base = (size_t)(p0 + pr) * 512 + c0 + cb;
#pragma unroll
        for (int s = 0; s < 4; s++) {
            *(ushort4*)(xh + base + s * 4) = *(ushort4*)(hi + s * 4);
            *(ushort4*)(xl + base + s * 4) = *(ushort4*)(lo + s * 4);
        }
    }
}

__global__ __launch_bounds__(256) void trans_kernel(
    const void* x_f32, const void* x_b16, const int* __restrict__ dflag,
    u16* xh, u16* xl)
{
    __shared__ float T[64][65];
    if (*dflag) trans_body<true >(x_f32, xh, xl, T);
    else        trans_body<false>(x_b16, xh, xl, T);
}

// ---------------------------------------------------------------------------
// 8-wave BK=64 MFMA family: 512 threads = 2x4 waves; wave (wr,wc) owns a
// 64x32 sub-tile; acc[4][2] of f32x4.  LDS tiles [128 rows][64 k] bf16 with
// full 8-slot XOR swizzle: LDS slot c holds global k-chunk (c ^ (row&7)).
// Each wave stages 16 rows x 64 k per operand = 2 gl2lds16 calls; row&7 is
// equal for both calls (delta 8) so the per-lane source chunk is shared.
// 16 MFMA per barrier pair (2 k-halves of 32).
// ---------------------------------------------------------------------------
#define FRAG_OFFS_A64(arr)                                          \
    int arr[4][2];                                                  \
    _Pragma("unroll")                                               \
    for (int ii = 0; ii < 4; ii++) {                                \
        int row = wr * 64 + ii * 16 + fr;                           \
        _Pragma("unroll")                                           \
        for (int hf = 0; hf < 2; hf++)                              \
            arr[ii][hf] = row * 64 + (((hf * 4 + fq) ^ (row & 7)) * 8); \
    }
#define FRAG_OFFS_B64(arr)                                          \
    int arr[2][2];                                                  \
    _Pragma("unroll")                                               \
    for (int ii = 0; ii < 2; ii++) {                                \
        int row = wc * 32 + ii * 16 + fr;                           \
        _Pragma("unroll")                                           \
        for (int hf = 0; hf < 2; hf++)                              \
            arr[ii][hf] = row * 64 + (((hf * 4 + fq) ^ (row & 7)) * 8); \
    }

// ---------------------------------------------------------------------------
// K1: MFMA split-GEMM projection (8-wave, BK=64).
// Tile 0 (o0=0, q/k): K'=1536 (x_hi.W_hi | x_hi.W_lo | x_lo.W_hi) ~ fp32.
// Tiles 1..4 (V): K'=512, single x_hi.W_hi term (bf16 v storage dominates).
// q -> q2 bf16 [p][128] = [q_hi|q_lo]; k -> k2 likewise; v -> v_c bf16 [c][p].
// ---------------------------------------------------------------------------
__global__ __launch_bounds__(512) void projmm_kernel(
    const u16* __restrict__ xT_hi, const u16* __restrict__ xT_lo,
    const u16* __restrict__ W_hi,  const u16* __restrict__ W_lo,
    const float* __restrict__ bcat,
    u16* __restrict__ q2, u16* __restrict__ k2, u16* __restrict__ v_c)
{
    __shared__ __align__(16) u16 Asl[128 * 64];
    __shared__ __align__(16) u16 Bsl[128 * 64];
    const int t = threadIdx.x;
    const int lane = t & 63, wid = t >> 6;      // wid 0..7
    const int wr = wid >> 2, wc = wid & 3;
    const int fr = lane & 15, fq = lane >> 4;
    const int p0 = blockIdx.x * 128;
    const int o0 = blockIdx.y * 128;
    const int KTOT = (blockIdx.y == 0) ? 1536 : 512;

    f32x4 acc[4][2];
#pragma unroll
    for (int i = 0; i < 4; i++)
#pragma unroll
        for (int j = 0; j < 2; j++) acc[i][j] = (f32x4){0.f, 0.f, 0.f, 0.f};

    const int srow_l = lane >> 3;               // 0..7
    const int gk     = ((lane & 7) ^ srow_l) * 8;
    const int row0   = wid * 16 + srow_l;       // 0..127
    const size_t gA0 = (size_t)(p0 + row0) * 512 + gk;
    const size_t gB0 = (size_t)(o0 + row0) * 512 + gk;
    u16* ldsA = Asl + wid * 1024;
    u16* ldsB = Bsl + wid * 1024;

    FRAG_OFFS_A64(aoff)
    FRAG_OFFS_B64(boff)

    for (int k0 = 0; k0 < KTOT; k0 += 64) {
        const int rg = k0 >> 9;          // 0,1,2 (uniform)
        const int kc = k0 & 511;
        const u16* xs   = (rg == 2) ? xT_lo : xT_hi;
        const u16* wsrc = (rg == 1) ? W_lo  : W_hi;
        gl2lds16(xs + gA0 + kc,            ldsA);
        gl2lds16(xs + gA0 + 8 * 512 + kc,  ldsA + 512);
        gl2lds16(wsrc + gB0 + kc,           ldsB);
        gl2lds16(wsrc + gB0 + 8 * 512 + kc, ldsB + 512);
        __syncthreads();

#pragma unroll
        for (int hf = 0; hf < 2; hf++) {
            bf16x8 av[4], bv2[2];
#pragma unroll
            for (int mi = 0; mi < 4; mi++) av[mi] = *(const bf16x8*)(Asl + aoff[mi][hf]);
#pragma unroll
            for (int ni = 0; ni < 2; ni++) bv2[ni] = *(const bf16x8*)(Bsl + boff[ni][hf]);
#pragma unroll
            for (int mi = 0; mi < 4; mi++)
#pragma unroll
                for (int ni = 0; ni < 2; ni++)
                    acc[mi][ni] = __builtin_amdgcn_mfma_f32_16x16x32_bf16(
                        av[mi], bv2[ni], acc[mi][ni], 0, 0, 0);
        }
        __syncthreads();
    }

    // epilogue: row p = p0+wr*64+mi*16+fq*4+r, col o = o0+wc*32+ni*16+fr
#pragma unroll
    for (int ni = 0; ni < 2; ni++) {
        const int o = o0 + wc * 32 + ni * 16 + fr;
        const float bb = bcat[o];
        if (o < 64) {
#pragma unroll
            for (int mi = 0; mi < 4; mi++) {
                const int pb = p0 + wr * 64 + mi * 16 + fq * 4;
#pragma unroll
                for (int r = 0; r < 4; r++) {
                    float val = acc[mi][ni][r] + bb;
                    u16 hi = f2bf(val);
                    q2[(size_t)(pb + r) * 128 + o]      = hi;
                    q2[(size_t)(pb + r) * 128 + 64 + o] = f2bf(val - bf2f(hi));
                }
            }
        } else if (o < 128) {
            const int oc = o - 64;
#pragma unroll
            for (int mi = 0; mi < 4; mi++) {
                const int pb = p0 + wr * 64 + mi * 16 + fq * 4;
#pragma unroll
                for (int r = 0; r < 4; r++) {
                    float val = acc[mi][ni][r] + bb;
                    u16 hi = f2bf(val);
                    k2[(size_t)(pb + r) * 128 + oc]      = hi;
                    k2[(size_t)(pb + r) * 128 + 64 + oc] = f2bf(val - bf2f(hi));
                }
            }
        } else {
            const int ch = o - 128;
#pragma unroll
            for (int mi = 0; mi < 4; mi++) {
                const int pb = p0 + wr * 64 + mi * 16 + fq * 4;
                ushort4 u = { f2bf(acc[mi][ni][0] + bb), f2bf(acc[mi][ni][1] + bb),
                              f2bf(acc[mi][ni][2] + bb), f2bf(acc[mi][ni][3] + bb) };
                *(ushort4*)(v_c + (size_t)ch * PP + pb) = u;
            }
        }
    }
}

// ---------------------------------------------------------------------------
// shared 128x128(K=128) bf16 MFMA core, 8-wave BK=64 variant (2 K-steps).
// ---------------------------------------------------------------------------
__device__ __forceinline__ void mm128_core8(
    const u16* __restrict__ baseA, size_t sA,
    const u16* __restrict__ baseB, size_t sB,
    u16* Asl, u16* Bsl, int lane, int wid,
    const int (*aoff)[2], const int (*boff)[2], f32x4 (*acc)[2])
{
    const int srow_l = lane >> 3;
    const int gk     = ((lane & 7) ^ srow_l) * 8;
    const int row0   = wid * 16 + srow_l;
    const u16* gA = baseA + (size_t)row0 * sA + gk;
    const u16* gB = baseB + (size_t)row0 * sB + gk;
    u16* ldsA = Asl + wid * 1024;
    u16* ldsB = Bsl + wid * 1024;
    for (int k0 = 0; k0 < 128; k0 += 64) {
        gl2lds16(gA + k0,           ldsA);
        gl2lds16(gA + 8 * sA + k0,  ldsA + 512);
        gl2lds16(gB + k0,           ldsB);
        gl2lds16(gB + 8 * sB + k0,  ldsB + 512);
        __syncthreads();
#pragma unroll
        for (int hf = 0; hf < 2; hf++) {
            bf16x8 av[4], bv2[2];
#pragma unroll
            for (int mi = 0; mi < 4; mi++) av[mi] = *(const bf16x8*)(Asl + aoff[mi][hf]);
#pragma unroll
            for (int ni = 0; ni < 2; ni++) bv2[ni] = *(const bf16x8*)(Bsl + boff[ni][hf]);
#pragma unroll
            for (int mi = 0; mi < 4; mi++)
#pragma unroll
                for (int ni = 0; ni < 2; ni++)
                    acc[mi][ni] = __builtin_amdgcn_mfma_f32_16x16x32_bf16(
                        av[mi], bv2[ni], acc[mi][ni], 0, 0, 0);
        }
        __syncthreads();
    }
}

// ---------------------------------------------------------------------------
// K2: fused energy (MFMA 8-wave BK=64, fp32-equivalent via hi/lo 3 terms).
// grid (128, 2): y=0 -> energy_H at w=blockIdx.x (rows h, stride 16384);
//                y=1 -> energy_W at h=blockIdx.x (rows w, stride 128).
// E = q_hi.k_hi + q_hi.k_lo + q_lo.k_hi  (3 K-steps of 64, slice-selected).
// ---------------------------------------------------------------------------
__global__ __launch_bounds__(512) void energy_mm_kernel(
    const u16* __restrict__ q2, const u16* __restrict__ k2,
    float* __restrict__ attn_f)
{
    __shared__ __align__(16) u16 Asl[128 * 64];
    __shared__ __align__(16) u16 Bsl[128 * 64];
    const int t = threadIdx.x;
    const int lane = t & 63, wid = t >> 6;
    const int wr = wid >> 2, wc = wid & 3;
    const int fr = lane & 15, fq = lane >> 4;
    const int isW = blockIdx.y;              // uniform
    const int fx  = blockIdx.x;

    const size_t sA   = isW ? 128 : (size_t)128 * 128;
    const size_t base = isW ? (size_t)fx * 128 * 128 : (size_t)fx * 128;

    f32x4 acc[4][2];
#pragma unroll
    for (int i = 0; i < 4; i++)
#pragma unroll
        for (int j = 0; j < 2; j++) acc[i][j] = (f32x4){0.f, 0.f, 0.f, 0.f};

    const int srow_l = lane >> 3;
    const int gk     = ((lane & 7) ^ srow_l) * 8;
    const int row0   = wid * 16 + srow_l;
    const u16* gA = q2 + base + (size_t)row0 * sA + gk;
    const u16* gB = k2 + base + (size_t)row0 * sA + gk;
    u16* ldsA = Asl + wid * 1024;
    u16* ldsB = Bsl + wid * 1024;

    FRAG_OFFS_A64(aoff)
    FRAG_OFFS_B64(boff)

    const int AO[3] = {0, 0, 64};    // q: hi hi lo
    const int BO[3] = {0, 64, 0};    // k: hi lo hi
#pragma unroll
    for (int s = 0; s < 3; s++) {
        gl2lds16(gA + AO[s],           ldsA);
        gl2lds16(gA + 8 * sA + AO[s],  ldsA + 512);
        gl2lds16(gB + BO[s],           ldsB);
        gl2lds16(gB + 8 * sA + BO[s],  ldsB + 512);
        __syncthreads();
#pragma unroll
        for (int hf = 0; hf < 2; hf++) {
            bf16x8 av[4], bv2[2];
#pragma unroll
            for (int mi = 0; mi < 4; mi++) av[mi] = *(const bf16x8*)(Asl + aoff[mi][hf]);
#pragma unroll
            for (int ni = 0; ni < 2; ni++) bv2[ni] = *(const bf16x8*)(Bsl + boff[ni][hf]);
#pragma unroll
            for (int mi = 0; mi < 4; mi++)
#pragma unroll
                for (int ni = 0; ni < 2; ni++)
                    acc[mi][ni] = __builtin_amdgcn_mfma_f32_16x16x32_bf16(
                        av[mi], bv2[ni], acc[mi][ni], 0, 0, 0);
        }
        __syncthreads();
    }

    // epilogue: M index rm (h for eH, w for eW); N index cn (i or j)
#pragma unroll
    for (int ni = 0; ni < 2; ni++) {
        const int cn = wc * 32 + ni * 16 + fr;
#pragma unroll
        for (int mi = 0; mi < 4; mi++) {
            const int rm0 = wr * 64 + mi * 16 + fq * 4;
#pragma unroll
            for (int r = 0; r < 4; r++) {
                const int rm = rm0 + r;
                const size_t prow = isW ? ((size_t)fx * 128 + rm)
                                        : ((size_t)rm * 128 + fx);
                float vv = acc[mi][ni][r];
                if (!isW && cn == rm) vv = NEG_BIG;
                attn_f[prow * 256 + (size_t)isW * 128 + cn] = vv;
            }
        }
    }
}

// ---------------------------------------------------------------------------
// K3: fused softmax + v-transpose, ONE launch (independent block roles).
//   blocks [0,4096): softmax over 256, one wave per row, fp32 -> bf16.
//   blocks [4096,5120): v_a[c][w*128+h] = v_c[c][h*128+w]  (64-wide w slab).
// v_a lives in the xT_lo region (dead after projmm) so the two roles touch
// disjoint buffers and can overlap freely.
// ---------------------------------------------------------------------------
__global__ __launch_bounds__(256) void smvt_kernel(
    const float* __restrict__ attn_f, u16* __restrict__ attn_b,
    const u16* __restrict__ v_c, u16* __restrict__ v_a)
{
    __shared__ __align__(16) u16 T[64 * 132];   // vtrans staging only
    const int bid = blockIdx.x;
    const int t = threadIdx.x;
    if (bid < 4096) {
        const int wave = t >> 6, lane = t & 63;
        const size_t row = (size_t)bid * 4 + wave;
        const float* rp = attn_f + row * 256;
        float4 v = ((const float4*)rp)[lane];
        v.x = isfinite(v.x) ? v.x : NEG_BIG;
        v.y = isfinite(v.y) ? v.y : NEG_BIG;
        v.z = isfinite(v.z) ? v.z : NEG_BIG;
        v.w = isfinite(v.w) ? v.w : NEG_BIG;
        float m = fmaxf(fmaxf(v.x, v.y), fmaxf(v.z, v.w));
#pragma unroll
        for (int off = 32; off; off >>= 1) m = fmaxf(m, __shfl_xor(m, off));
        float e0 = __expf(v.x - m), e1 = __expf(v.y - m);
        float e2 = __expf(v.z - m), e3 = __expf(v.w - m);
        float s = e0 + e1 + e2 + e3;
#pragma unroll
        for (int off = 32; off; off >>= 1) s += __shfl_xor(s, off);
        float inv = 1.0f / s;
        ushort4 u = { f2bf(e0 * inv), f2bf(e1 * inv), f2bf(e2 * inv), f2bf(e3 * inv) };
        ((ushort4*)(attn_b + row * 256))[lane] = u;
    } else {
        const int vb = bid - 4096;
        const int c  = vb & 511;
        const int w0 = (vb >> 9) * 64;
#pragma unroll
        for (int s = 0; s < 4; s++) {
            const int h  = (t >> 3) + s * 32;
            const int wl = (t & 7) * 8;
            const u16* src = v_c + (size_t)c * PP + h * 128 + w0 + wl;
            ushort4 a0 = *(const ushort4*)(src);
            ushort4 a1 = *(const ushort4*)(src + 4);
            T[(wl + 0) * 132 + h] = a0.x; T[(wl + 1) * 132 + h] = a0.y;
            T[(wl + 2) * 132 + h] = a0.z; T[(wl + 3) * 132 + h] = a0.w;
            T[(wl + 4) * 132 + h] = a1.x; T[(wl + 5) * 132 + h] = a1.y;
            T[(wl + 6) * 132 + h] = a1.z; T[(wl + 7) * 132 + h] = a1.w;
        }
        __syncthreads();
#pragma unroll
        for (int s = 0; s < 4; s++) {
            const int wl = (t >> 4) + s * 16;
            const int hh = (t & 15) * 8;
            ushort4 b0 = *(const ushort4*)(T + wl * 132 + hh);
            ushort4 b1 = *(const ushort4*)(T + wl * 132 + hh + 4);
            ushort4* dp = (ushort4*)(v_a + (size_t)c * PP + (size_t)(w0 + wl) * 128 + hh);
            dp[0] = b0; dp[1] = b1;
        }
    }
}

// ---------------------------------------------------------------------------
// K5: aggA (MFMA 8-wave BK=64).  Per (c-tile, w):
//   D[h][c] = sum_i attnH[h,w,i] * v_a[c][w*128+i]
// out_t[(h*128+w)*512 + c] bf16 via LDS re-coalesce.  Dst aliases Asl/Bsl
// (dead after the K-loop) -> static LDS 33 KB.
// ---------------------------------------------------------------------------
__global__ __launch_bounds__(512) void aggA_mm_kernel(
    const u16* __restrict__ v_a, const u16* __restrict__ attn_b,
    u16* __restrict__ out_t)
{
    __shared__ __align__(16) char smem[128 * 132 * 2];  // >= 2x16KB gemm tiles
    u16* Asl = (u16*)smem;
    u16* Bsl = (u16*)(smem + 128 * 64 * 2);
    u16* Dst = (u16*)smem;                               // [128][132] after loop
    const int t = threadIdx.x;
    const int lane = t & 63, wid = t >> 6;
    const int wr = wid >> 2, wc = wid & 3;
    const int fr = lane & 15, fq = lane >> 4;
    const int c0 = blockIdx.x * 128;
    const int w  = blockIdx.y;

    f32x4 acc[4][2];
#pragma unroll
    for (int i = 0; i < 4; i++)
#pragma unroll
        for (int j = 0; j < 2; j++) acc[i][j] = (f32x4){0.f, 0.f, 0.f, 0.f};

    FRAG_OFFS_A64(aoff)
    FRAG_OFFS_B64(boff)

    // A: rows h, stride 128*256 elems; base attn_b + w*256 (H-half of row)
    // B: rows c, stride PP; base v_a + c0*PP + w*128
    mm128_core8(attn_b + (size_t)w * 256, (size_t)128 * 256,
                v_a + (size_t)c0 * PP + (size_t)w * 128, (size_t)PP,
                Asl, Bsl, lane, wid, aoff, boff, acc);

    // stage D[h][c] -> Dst (bf16), then coalesced 256B-row writes
#pragma unroll
    for (int mi = 0; mi < 4; mi++)
#pragma unroll
        for (int ni = 0; ni < 2; ni++) {
            const int c = wc * 32 + ni * 16 + fr;
#pragma unroll
            for (int r = 0; r < 4; r++) {
                const int h = wr * 64 + mi * 16 + fq * 4 + r;
                Dst[h * 132 + c] = f2bf(acc[mi][ni][r]);
            }
        }
    __syncthreads();
#pragma unroll
    for (int s = 0; s < 4; s++) {
        const int h = s * 32 + (t >> 4);
        const int c = (t & 15) * 8;
        ushort4 a0 = *(const ushort4*)(Dst + h * 132 + c);
        ushort4 a1 = *(const ushort4*)(Dst + h * 132 + c + 4);
        ushort4* dp = (ushort4*)(out_t + (size_t)(h * WW + w) * 512 + c0 + c);
        dp[0] = a0; dp[1] = a1;
    }
}

// ---------------------------------------------------------------------------
// K6: aggB (MFMA 8-wave BK=64) + fused epilogue.  Per (c-tile, h):
//   D[w][c] = sum_j attnW[h,w,j] * v_c[c][h*128+j]
//   out[c][h][w] = gamma*(D + out_t) + x   (x/out pre-offset per batch)
// epi aliases Asl/Bsl (dead after the K-loop) -> static LDS 34 KB.
// ---------------------------------------------------------------------------
template<bool F32>
__device__ __forceinline__ void aggB_mm_body(
    const u16* __restrict__ v_c, const u16* __restrict__ attn_b,
    const u16* __restrict__ out_t, const void* __restrict__ x,
    const void* __restrict__ gamma, void* __restrict__ out,
    char* smem)
{
    u16* Asl = (u16*)smem;
    u16* Bsl = (u16*)(smem + 128 * 64 * 2);
    char* epi = smem;
    const int t = threadIdx.x;
    const int lane = t & 63, wid = t >> 6;
    const int wr = wid >> 2, wc = wid & 3;
    const int fr = lane & 15, fq = lane >> 4;
    const int c0 = blockIdx.x * 128;
    const int h  = blockIdx.y;

    f32x4 acc[4][2];
#pragma unroll
    for (int i = 0; i < 4; i++)
#pragma unroll
        for (int j = 0; j < 2; j++) acc[i][j] = (f32x4){0.f, 0.f, 0.f, 0.f};

    FRAG_OFFS_A64(aoff)
    FRAG_OFFS_B64(boff)

    // A: rows w, stride 256, base attn_b + h*128*256 + 128 (W-half)
    // B: rows c, stride PP, base v_c + c0*PP + h*128
    mm128_core8(attn_b + (size_t)h * 128 * 256 + 128, (size_t)256,
                v_c + (size_t)c0 * PP + (size_t)h * 128, (size_t)PP,
                Asl, Bsl, lane, wid, aoff, boff, acc);

    // 1) stage out_t tile -> OAs[w][c] (pad 136), coalesced reads
    u16* OAs = (u16*)epi;
#pragma unroll
    for (int s = 0; s < 4; s++) {
        const int wrow = s * 32 + (t >> 4);
        const int c = (t & 15) * 8;
        const u16* sp = out_t + (size_t)(h * WW + wrow) * 512 + c0 + c;
        ushort4 a0 = *(const ushort4*)(sp);
        ushort4 a1 = *(const ushort4*)(sp + 4);
        *(ushort4*)(OAs + wrow * 136 + c)     = a0;
        *(ushort4*)(OAs + wrow * 136 + c + 4) = a1;
    }
    __syncthreads();
    // 2) acc += OA
#pragma unroll
    for (int mi = 0; mi < 4; mi++)
#pragma unroll
        for (int ni = 0; ni < 2; ni++) {
            const int c = wc * 32 + ni * 16 + fr;
#pragma unroll
            for (int r = 0; r < 4; r++) {
                const int ww = wr * 64 + mi * 16 + fq * 4 + r;
                acc[mi][ni][r] += bf2f(OAs[ww * 136 + c]);
            }
        }
    __syncthreads();   // OAs consumed; reuse as DstF

    const float g = ldg<F32>(gamma, 0);
    float* DstF = (float*)epi;       // [64][132] fp32
#pragma unroll
    for (int half = 0; half < 2; half++) {
        if ((wc >> 1) == half) {
#pragma unroll
            for (int mi = 0; mi < 4; mi++)
#pragma unroll
                for (int ni = 0; ni < 2; ni++) {
                    const int cl = (wc & 1) * 32 + ni * 16 + fr;
                    const int w0 = wr * 64 + mi * 16 + fq * 4;
                    f32x4 vv = acc[mi][ni];
                    *(f32x4*)(DstF + cl * 132 + w0) = vv;
                }
        }
        __syncthreads();
#pragma unroll
        for (int s = 0; s < 4; s++) {
            const int e  = s * 2048 + t * 4;
            const int cl = e >> 7;
            const int wq = e & 127;
            f32x4 vv = *(const f32x4*)(DstF + cl * 132 + wq);
            const size_t base = (size_t)(c0 + half * 64 + cl) * PP + h * 128 + wq;
            float r0 = g * vv[0] + ldg<F32>(x, base + 0);
            float r1 = g * vv[1] + ldg<F32>(x, base + 1);
            float r2 = g * vv[2] + ldg<F32>(x, base + 2);
            float r3 = g * vv[3] + ldg<F32>(x, base + 3);
            if (F32) {
                *(float4*)((float*)out + base) = make_float4(r0, r1, r2, r3);
            } else {
                ushort4 o = { f2bf(r0), f2bf(r1), f2bf(r2), f2bf(r3) };
                *(ushort4*)((u16*)out + base) = o;
            }
        }
        __syncthreads();
    }
}

__global__ __launch_bounds__(512) void aggB_mm_kernel(
    const u16* v_c, const u16* attn_b, const u16* out_t,
    const void* x_f32, const void* x_b16, const void* gamma,
    const int* __restrict__ dflag, void* out_f32, void* out_b16)
{
    __shared__ __align__(16) char smem[128 * 136 * 2];  // >= 2x16KB gemm tiles
    if (*dflag)
        aggB_mm_body<true >(v_c, attn_b, out_t, x_f32, gamma, out_f32, smem);
    else
        aggB_mm_body<false>(v_c, attn_b, out_t, x_b16, gamma, out_b16, smem);
}

// ---------------------------------------------------------------------------
extern "C" void kernel_launch(void* const* d_in, const int* in_sizes, int n_in,
                              void* d_out, int out_size, void* d_ws, size_t ws_size,
                              hipStream_t stream)
{
    const void* x     = d_in[0];
    const void* Wq    = d_in[1];
    const void* bq    = d_in[2];
    const void* Wk    = d_in[3];
    const void* bk    = d_in[4];
    const void* Wv    = d_in[5];
    const void* bv    = d_in[6];
    const void* gamma = d_in[7];

    // workspace (~57.3 MiB peak — proven footprint):
    //   dflag | bcat | W_hi/W_lo bf16 | q2 bf16 [p][128] 4MiB | k2 4MiB |
    //   v_c bf16 [c][p] 16MiB | xT_hi 16MiB | xT_lo 16MiB.
    // Overlays (order: trans, projmm, energy, smvt, aggA, aggB):
    //   attn_f fp32 16MiB = xT_hi (xT_hi dead after projmm)
    //   out_t  bf16 16MiB = xT_hi (attn_f dead after smvt's softmax; aggA after)
    //   v_a    bf16 16MiB = xT_lo (xT_lo dead after projmm; enables sm||vt fuse)
    //   attn_b bf16  8MiB = q2+k2 (dead after energy)
    char* ws = (char*)d_ws;
    int*   dflag = (int*)ws;
    float* bcat  = (float*)(ws + 256);
    size_t off = 4096;
    u16* W_hi = (u16*)(ws + off); off += (size_t)640 * 512 * 2;
    u16* W_lo = (u16*)(ws + off); off += (size_t)640 * 512 * 2;
    u16* q2   = (u16*)(ws + off); off += (size_t)PP * 128 * 2;
    u16* k2   = (u16*)(ws + off); off += (size_t)PP * 128 * 2;
    u16* v_c   = (u16*)(ws + off);  off += (size_t)PP * 512 * 2;
    u16* xT_hi = (u16*)(ws + off);  off += (size_t)PP * 512 * 2;
    u16* xT_lo = (u16*)(ws + off);  off += (size_t)PP * 512 * 2;
    float* attn_f = (float*)xT_hi;
    u16*   out_t  = (u16*)xT_hi;
    u16*   v_a    = (u16*)xT_lo;
    u16*   attn_b = (u16*)q2;

    detect_kernel<<<dim3(1), 256, 0, stream>>>(x, dflag);
    wconv_kernel<<<dim3(640), 256, 0, stream>>>(
        Wq, bq, Wk, bk, Wv, bv, dflag, W_hi, W_lo, bcat);

    for (int b = 0; b < BB; b++) {
        const void* x_f = (const void*)((const float*)x + (size_t)b * CC * PP);
        const void* x_h = (const void*)((const u16*)x   + (size_t)b * CC * PP);
        void* o_f = (void*)((float*)d_out + (size_t)b * CC * PP);
        void* o_h = (void*)((u16*)d_out   + (size_t)b * CC * PP);
        trans_kernel<<<dim3(PP / 64, CC / 64), 256, 0, stream>>>(
            x_f, x_h, dflag, xT_hi, xT_lo);
        projmm_kernel<<<dim3(PP / 128, 5), 512, 0, stream>>>(
            xT_hi, xT_lo, W_hi, W_lo, bcat, q2, k2, v_c);
        energy_mm_kernel<<<dim3(128, 2), 512, 0, stream>>>(q2, k2, attn_f);
        smvt_kernel<<<dim3(PP / 4 + CC * 2), 256, 0, stream>>>(
            attn_f, attn_b, v_c, v_a);
        aggA_mm_kernel<<<dim3(4, WW), 512, 0, stream>>>(v_a, attn_b, out_t);
        aggB_mm_kernel<<<dim3(4, HH), 512, 0, stream>>>(
            v_c, attn_b, out_t, x_f, x_h, gamma, dflag, o_f, o_h);
    }
}